// Round 7
// baseline (564.641 us; speedup 1.0000x reference)
//
#include <hip/hip_runtime.h>
#include <hip/hip_bf16.h>

#define N 8192
#define D 512
#define K_TOP 12
#define THETA 10.0f
#define EPS 1e-8f
#define TAU 0.10f      // candidate threshold; spill+fallback guarantee the guard
#define CAPL 6         // per-row per-pair LDS cap (overflow -> exact global spill)
#define CAPG 188       // per-row global candidate cap (shrunk 192->188 to fit sync flags)
#define NPAIR 2080     // 64*65/2 upper-triangular 128x128 tile pairs
#define NBLK 1024      // persistent blocks: exactly 4/CU, co-resident by construction

typedef float f32x16 __attribute__((ext_vector_type(16)));

__device__ __forceinline__ unsigned int bf16_bits_rne(float v) {
    unsigned int u = __float_as_uint(v);
    u += 0x7FFFu + ((u >> 16) & 1u);
    return u >> 16;
}

// async global->LDS DMA, 16B per lane; LDS dest is wave-uniform base + lane*16
__device__ __forceinline__ void load16(const unsigned char* g, unsigned char* l) {
    __builtin_amdgcn_global_load_lds(
        (const __attribute__((address_space(1))) unsigned int*)g,
        (__attribute__((address_space(3))) unsigned int*)l, 16, 0, 0);
}

// column-major (jt-major) triangle decode: p = jt*(jt+1)/2 + it, it in [0,jt]
__device__ __forceinline__ void decode_pair(int p, int& it, int& jt) {
    int j = (int)((sqrtf(8.0f * (float)p + 1.0f) - 1.0f) * 0.5f);
    while ((j + 1) * (j + 2) / 2 <= p) ++j;
    while (j * (j + 1) / 2 > p) --j;
    jt = j;
    it = p - j * (j + 1) / 2;
}

// -- Fused kernel: norm -> (tile-ready flags) -> sim -> (tile-done flags) ->
//    gather. Plain launch; 1024 blocks x 256 thr, 39936 B LDS, 4 blocks/CU =
//    all co-resident, so flag spins cannot deadlock (phase graph is a DAG).
// syncv[x] packs: low 16 bits = ready count (target 16 norm blocks/tile),
//                 high bits  = done count x 65536 (target 64 pairs/tile).
__global__ __launch_bounds__(256, 4) void fused_kernel(
        const float* __restrict__ h,
        unsigned char* __restrict__ hq,
        float* __restrict__ norms,
        unsigned int* __restrict__ gcand,
        int* __restrict__ gcnt,
        int* __restrict__ gflag,
        int* __restrict__ syncv,
        float* __restrict__ out) {
    __shared__ unsigned char tiles[2][2][128 * 64];  // [sel][A/B] 32 KB
    __shared__ int cnt[256];                          // 1 KB
    __shared__ unsigned int lbuf[256][CAPL];          // 6 KB

    const int b = blockIdx.x;
    const int t = threadIdx.x;
    const int wave = t >> 6, lane = t & 63;

    // ===== Phase A: norm + fp8 quant, 8 rows/block; zero per-row counters ====
#pragma unroll
    for (int rr = 0; rr < 2; rr++) {
        int row = b * 8 + wave * 2 + rr;
        const float4* hr4 = (const float4*)(h + (size_t)row * D);
        float4 p0 = hr4[lane], p1 = hr4[64 + lane];
        float ss = p0.x * p0.x + p0.y * p0.y + p0.z * p0.z + p0.w * p0.w +
                   p1.x * p1.x + p1.y * p1.y + p1.z * p1.z + p1.w * p1.w;
#pragma unroll
        for (int off = 32; off > 0; off >>= 1) ss += __shfl_xor(ss, off, 64);
        float nrm = fmaxf(sqrtf(ss), EPS);
        float inv = 1.0f / nrm;
        if (lane == 0) { gcnt[row] = 0; gflag[row] = 0; norms[row] = nrm; }
        unsigned int w0 = __builtin_amdgcn_cvt_pk_fp8_f32(p0.x * inv, p0.y * inv, 0, false);
        w0 = __builtin_amdgcn_cvt_pk_fp8_f32(p0.z * inv, p0.w * inv, w0, true);
        unsigned int w1 = __builtin_amdgcn_cvt_pk_fp8_f32(p1.x * inv, p1.y * inv, 0, false);
        w1 = __builtin_amdgcn_cvt_pk_fp8_f32(p1.z * inv, p1.w * inv, w1, true);
        unsigned int* q32 = (unsigned int*)(hq + (size_t)row * D);
        q32[lane] = w0;
        q32[64 + lane] = w1;
    }
    cnt[t] = 0;
    __syncthreads();
    if (t == 0) {
        __threadfence();   // hq/norms/gcnt writes visible device-wide
        __hip_atomic_fetch_add(&syncv[b >> 4], 1, __ATOMIC_RELEASE,
                               __HIP_MEMORY_SCOPE_AGENT);
    }

    auto wait_ready2 = [&](int ta, int tb) {
        if (t == 0) {
            while ((__hip_atomic_load(&syncv[ta], __ATOMIC_ACQUIRE,
                                      __HIP_MEMORY_SCOPE_AGENT) & 0xFFFF) < 16)
                __builtin_amdgcn_s_sleep(8);
            while ((__hip_atomic_load(&syncv[tb], __ATOMIC_ACQUIRE,
                                      __HIP_MEMORY_SCOPE_AGENT) & 0xFFFF) < 16)
                __builtin_amdgcn_s_sleep(8);
        }
        __syncthreads();
    };

    // ===== Phase B: symmetric fp8 MFMA sim (R3 dbuf-K64 structure) ===========
    {
        const int wr = (wave >> 1) * 64, wc = (wave & 1) * 64;
        const int lm32 = lane & 31, lg2 = lane >> 5;
        const int rk = (lm32 >> 2) & 3;  // read-side swizzle key ((row>>2)&3)
        const int srow = t >> 2;
        const int sq = (t & 3) ^ ((t >> 4) & 3);

        auto issue = [&](int ii0, int jj0, int r_) {
            int sel = r_ & 1;   // 8 rounds/pair (even) keeps parity global
            const unsigned char* gA = hq + (size_t)(ii0 + srow) * D + r_ * 64 + sq * 16;
            const unsigned char* gB = hq + (size_t)(jj0 + srow) * D + r_ * 64 + sq * 16;
            unsigned char* lA = &tiles[sel][0][t * 16];
            unsigned char* lB = &tiles[sel][1][t * 16];
#pragma unroll
            for (int e = 0; e < 2; e++) {
                load16(gA + (size_t)(e * 64) * D, lA + e * 4096);
                load16(gB + (size_t)(e * 64) * D, lB + e * 4096);
            }
        };

        const int nloc = (b + 2048 < NPAIR) ? 3 : 2;   // blocks 0..31: 3rd pair

        int cit, cjt;
        decode_pair(b, cit, cjt);
        int ci0 = cit * 128, cj0 = cjt * 128;
        bool cdiag = (cit == cjt);
        wait_ready2(cit, cjt);
        issue(ci0, cj0, 0);

        f32x16 acc[2][2];
#pragma unroll
        for (int x = 0; x < 2; x++)
#pragma unroll
            for (int y = 0; y < 2; y++)
#pragma unroll
                for (int q = 0; q < 16; q++) acc[x][y][q] = 0.f;

        for (int qp = 0; qp < nloc; qp++) {
            int nit = 0, njt = 0, ni0 = 0, nj0 = 0;
            bool ndiag = false;
            if (qp + 1 < nloc) {
                decode_pair(b + (qp + 1) * NBLK, nit, njt);
                ni0 = nit * 128; nj0 = njt * 128; ndiag = (nit == njt);
            }

            for (int r = 0; r < 8; r++) {
                const int sel = r & 1;

                __builtin_amdgcn_s_barrier();   // prior reads of buffer sel done
                if (r < 7) {
                    issue(ci0, cj0, r + 1);
                    asm volatile("s_waitcnt vmcnt(4)" ::: "memory");  // drain rnd r
                } else if (qp + 1 < nloc) {
                    wait_ready2(nit, njt);       // next pair's tiles quantized
                    issue(ni0, nj0, 0);          // prime next pair's round 0
                    asm volatile("s_waitcnt vmcnt(4)" ::: "memory");
                } else {
                    asm volatile("s_waitcnt vmcnt(0)" ::: "memory");
                }
                __builtin_amdgcn_s_barrier();   // round r fully in LDS

#pragma unroll
                for (int kk = 0; kk < 4; kk++) {   // 4 x K16 fp8 MFMA = K64
                    const int kb = ((kk ^ rk) << 4) + lg2 * 8;  // swizzled offset
                    long long af[2], bfr[2];
#pragma unroll
                    for (int x = 0; x < 2; x++)
                        af[x] = *(const long long*)&tiles[sel][0][(wr + x * 32 + lm32) * 64 + kb];
#pragma unroll
                    for (int y = 0; y < 2; y++)
                        bfr[y] = *(const long long*)&tiles[sel][1][(wc + y * 32 + lm32) * 64 + kb];
#pragma unroll
                    for (int x = 0; x < 2; x++)
#pragma unroll
                        for (int y = 0; y < 2; y++)
                            acc[x][y] = __builtin_amdgcn_mfma_f32_32x32x16_fp8_fp8(
                                af[x], bfr[y], acc[x][y], 0, 0, 0);
                }
            }

            // emit candidates two-sided into LDS; reset acc for next pair.
            // 32x32 C/D: col = lane&31, row = (reg&3) + 8*(reg>>2) + 4*(lane>>5)
#pragma unroll
            for (int x = 0; x < 2; x++)
#pragma unroll
                for (int y = 0; y < 2; y++) {
                    int lcol = wc + y * 32 + lm32;
                    int gcol = cj0 + lcol;
#pragma unroll
                    for (int q = 0; q < 16; q++) {
                        int rr = wr + x * 32 + (q & 3) + 8 * (q >> 2) + 4 * lg2;
                        int gi = ci0 + rr;
                        float v = acc[x][y][q];
                        acc[x][y][q] = 0.f;
                        if (gi == gcol) v = 1.0f;   // exact self-sim (diag pairs)
                        if (v > TAU) {
                            unsigned int vb = bf16_bits_rne(v) << 16;
                            int idx = atomicAdd(&cnt[rr], 1);
                            if (idx < CAPL) lbuf[rr][idx] = vb | (unsigned int)gcol;
                            else {  // rare exact spill straight to global
                                int pg = atomicAdd(&gcnt[gi], 1);
                                if (pg < CAPG) gcand[(size_t)gi * CAPG + pg] = vb | (unsigned int)gcol;
                                else gflag[gi] = 1;
                            }
                            if (!cdiag) {   // mirrored entry for the j-side row
                                int idx2 = atomicAdd(&cnt[128 + lcol], 1);
                                if (idx2 < CAPL) lbuf[128 + lcol][idx2] = vb | (unsigned int)gi;
                                else {
                                    int pg = atomicAdd(&gcnt[gcol], 1);
                                    if (pg < CAPG) gcand[(size_t)gcol * CAPG + pg] = vb | (unsigned int)gi;
                                    else gflag[gcol] = 1;
                                }
                            }
                        }
                    }
                }

            __syncthreads();   // all emissions visible block-wide
            {
                int grow = (t < 128) ? (ci0 + t) : (cj0 + t - 128);
                int c = cnt[t];
                int s = c < CAPL ? c : CAPL;
                if (s > 0) {   // diag pairs: j-side cnt stays 0, auto-skipped
                    int base = atomicAdd(&gcnt[grow], s);
                    unsigned int* dst = gcand + (size_t)grow * CAPG;
                    for (int k = 0; k < s; k++) {
                        int pp = base + k;
                        if (pp < CAPG) dst[pp] = lbuf[t][k];
                        else gflag[grow] = 1;
                    }
                }
                cnt[t] = 0;   // owner-thread reset; next emit is 8 barriers away
            }
            __syncthreads();   // flush stores complete before done-signal
            if (t == 0) {
                __threadfence();
                __hip_atomic_fetch_add(&syncv[cit], 65536, __ATOMIC_RELEASE,
                                       __HIP_MEMORY_SCOPE_AGENT);
                if (cit != cjt)
                    __hip_atomic_fetch_add(&syncv[cjt], 65536, __ATOMIC_RELEASE,
                                           __HIP_MEMORY_SCOPE_AGENT);
            }

            ci0 = ni0; cj0 = nj0; cdiag = ndiag; cit = nit; cjt = njt;
        }
    }

    // ===== Phase C: exact top-12 + softmax + gather (8 rows/block) ===========
    if (t == 0) {
        while ((__hip_atomic_load(&syncv[b >> 4], __ATOMIC_ACQUIRE,
                                  __HIP_MEMORY_SCOPE_AGENT) >> 16) < 64)
            __builtin_amdgcn_s_sleep(8);
    }
    __syncthreads();
    __threadfence();   // acquire for all lanes before reading gcand/gcnt

#pragma unroll 1
    for (int rr = 0; rr < 2; rr++) {
        int row = b * 8 + wave * 2 + rr;

        // early self-row prefetch: row is always its own top-1 (sim = 1.0)
        const float4* hr4 = (const float4*)(h + (size_t)row * D);
        float4 s0 = hr4[lane], s1 = hr4[64 + lane];

        int c = gcnt[row];

        float selv[K_TOP];
        int selj[K_TOP];

        if (c >= K_TOP && c <= CAPG && gflag[row] == 0) {
            const unsigned int* cr = gcand + (size_t)row * CAPG;
            unsigned int e[3];
#pragma unroll
            for (int q = 0; q < 3; q++) {
                int idx = lane + 64 * q;
                e[q] = (idx < c) ? cr[idx] : 0u;
            }
#pragma unroll
            for (int k = 0; k < K_TOP; k++) {
                unsigned int m = e[0];
                if (e[1] > m) m = e[1];
                if (e[2] > m) m = e[2];
#pragma unroll
                for (int off = 32; off > 0; off >>= 1) {
                    unsigned int om = __shfl_xor(m, off, 64);
                    if (om > m) m = om;
                }
                selv[k] = __uint_as_float(m & 0xFFFF0000u);
                selj[k] = (int)(m & 0x1FFFu);
#pragma unroll
                for (int q = 0; q < 3; q++)
                    if (e[q] == m) e[q] = 0u;   // entries unique (distinct cols)
            }
        } else {
            // exact brute-force fallback over fp8 rows (rare; cheap insurance)
            float vals[K_TOP];
            int idxs[K_TOP];
#pragma unroll
            for (int q = 0; q < K_TOP; q++) { vals[q] = -3e38f; idxs[q] = 0; }
            float minv = -3e38f;
            int minp = 0;
            const unsigned int* rp = (const unsigned int*)(hq + (size_t)row * D);
            for (int col = lane; col < N; col += 64) {
                const unsigned int* cp = (const unsigned int*)(hq + (size_t)col * D);
                float s = 0.f;
                for (int k4 = 0; k4 < D / 4; k4++) {
                    unsigned int ra = rp[k4], ca = cp[k4];
                    s += __builtin_amdgcn_cvt_f32_fp8(ra, 0) * __builtin_amdgcn_cvt_f32_fp8(ca, 0);
                    s += __builtin_amdgcn_cvt_f32_fp8(ra, 1) * __builtin_amdgcn_cvt_f32_fp8(ca, 1);
                    s += __builtin_amdgcn_cvt_f32_fp8(ra, 2) * __builtin_amdgcn_cvt_f32_fp8(ca, 2);
                    s += __builtin_amdgcn_cvt_f32_fp8(ra, 3) * __builtin_amdgcn_cvt_f32_fp8(ca, 3);
                }
                if (col == row) s = 1.0f;
                if (s > minv) {
                    vals[minp] = s; idxs[minp] = col;
                    minv = vals[0]; minp = 0;
#pragma unroll
                    for (int q = 1; q < K_TOP; q++)
                        if (vals[q] < minv) { minv = vals[q]; minp = q; }
                }
            }
            for (int k = 0; k < K_TOP; k++) {
                float bv = vals[0]; int bp = 0;
#pragma unroll
                for (int q = 1; q < K_TOP; q++)
                    if (vals[q] > bv) { bv = vals[q]; bp = q; }
                float v = bv; int j = idxs[bp]; int src = lane;
#pragma unroll
                for (int off = 32; off > 0; off >>= 1) {
                    float ov = __shfl_xor(v, off, 64);
                    int oj = __shfl_xor(j, off, 64);
                    int os = __shfl_xor(src, off, 64);
                    if (ov > v || (ov == v && os < src)) { v = ov; j = oj; src = os; }
                }
                selv[k] = __uint_as_float((unsigned int)(bf16_bits_rne(v) << 16));
                selj[k] = j;
                if (lane == src) vals[bp] = -3e38f;
            }
        }

        // batch-issue all neighbor fp8 row loads (12-deep MLP) + their norms
        unsigned int na[K_TOP], nb[K_TOP];
        float wn[K_TOP];
#pragma unroll
        for (int q = 0; q < K_TOP; q++) {
            const unsigned int* r32 = (const unsigned int*)(hq + (size_t)selj[q] * D);
            na[q] = r32[lane];
            nb[q] = r32[64 + lane];
            wn[q] = norms[selj[q]];
        }

        float mx = selv[0];
        float beta[K_TOP];
        float sum = 0.f;
#pragma unroll
        for (int q = 0; q < K_TOP; q++) { beta[q] = __expf(THETA * (selv[q] - mx)); sum += beta[q]; }
        float rs = 1.0f / sum;

        // lane owns output elems [lane*4,+4) and [256+lane*4,+4)
        float acc[8];
#pragma unroll
        for (int ee = 0; ee < 8; ee++) acc[ee] = 0.f;
#pragma unroll
        for (int q = 0; q < K_TOP; q++) {
            float w = beta[q] * rs;
            if (selj[q] == row) {   // wave-uniform; dominant term fp32-exact
                acc[0] += w * s0.x; acc[1] += w * s0.y; acc[2] += w * s0.z; acc[3] += w * s0.w;
                acc[4] += w * s1.x; acc[5] += w * s1.y; acc[6] += w * s1.z; acc[7] += w * s1.w;
            } else {                // neighbors (weight ~2e-4): fp8 row x norm
                float wj = w * wn[q];
                acc[0] += wj * __builtin_amdgcn_cvt_f32_fp8(na[q], 0);
                acc[1] += wj * __builtin_amdgcn_cvt_f32_fp8(na[q], 1);
                acc[2] += wj * __builtin_amdgcn_cvt_f32_fp8(na[q], 2);
                acc[3] += wj * __builtin_amdgcn_cvt_f32_fp8(na[q], 3);
                acc[4] += wj * __builtin_amdgcn_cvt_f32_fp8(nb[q], 0);
                acc[5] += wj * __builtin_amdgcn_cvt_f32_fp8(nb[q], 1);
                acc[6] += wj * __builtin_amdgcn_cvt_f32_fp8(nb[q], 2);
                acc[7] += wj * __builtin_amdgcn_cvt_f32_fp8(nb[q], 3);
            }
        }
        float4* o4 = (float4*)(out + (size_t)row * D);
        o4[lane] = make_float4(acc[0], acc[1], acc[2], acc[3]);
        o4[64 + lane] = make_float4(acc[4], acc[5], acc[6], acc[7]);
    }
}

extern "C" void kernel_launch(void* const* d_in, const int* in_sizes, int n_in,
                              void* d_out, int out_size, void* d_ws, size_t ws_size,
                              hipStream_t stream) {
    const float* h = (const float*)d_in[0];
    float* out = (float*)d_out;

    char* ws = (char*)d_ws;
    unsigned char* hq = (unsigned char*)ws;                      // 4 MB fp8
    size_t off = (size_t)N * D;
    float* norms = (float*)(ws + off);                           // 32 KB
    int* gcnt = (int*)(ws + off + (size_t)N * 4);                // 32 KB
    int* gflag = (int*)(ws + off + (size_t)N * 8);               // 32 KB
    unsigned int* gcand = (unsigned int*)(ws + off + (size_t)N * 12);  // ~6 MB
    int* syncv = (int*)(ws + off + (size_t)N * 12 + (size_t)N * CAPG * 4);  // 256 B

    hipMemsetAsync(syncv, 0, 64 * sizeof(int), stream);
    fused_kernel<<<NBLK, 256, 0, stream>>>(h, hq, norms, gcand, gcnt, gflag,
                                           syncv, out);
}

// Round 8
// 144.397 us; speedup vs baseline: 3.9103x; 3.9103x over previous
//
#include <hip/hip_runtime.h>
#include <hip/hip_bf16.h>

#define N 8192
#define D 512
#define K_TOP 12
#define THETA 10.0f
#define EPS 1e-8f
#define TAU 0.10f      // candidate threshold; spill+fallback guarantee the guard
#define CAPL 6         // per-row per-pair LDS cap (overflow -> exact global spill)
#define CAPG 192       // per-row global candidate cap
#define NPAIR 2080     // 64*65/2 upper-triangular 128x128 tile pairs
#define NBLK 1024      // persistent blocks: exactly 4/CU, one generation

typedef float f32x16 __attribute__((ext_vector_type(16)));

__device__ __forceinline__ unsigned int bf16_bits_rne(float v) {
    unsigned int u = __float_as_uint(v);
    u += 0x7FFFu + ((u >> 16) & 1u);
    return u >> 16;
}

// async global->LDS DMA, 16B per lane; LDS dest is wave-uniform base + lane*16
__device__ __forceinline__ void load16(const unsigned char* g, unsigned char* l) {
    __builtin_amdgcn_global_load_lds(
        (const __attribute__((address_space(1))) unsigned int*)g,
        (__attribute__((address_space(3))) unsigned int*)l, 16, 0, 0);
}

// column-major (jt-major) triangle decode: p = jt*(jt+1)/2 + it, it in [0,jt]
__device__ __forceinline__ void decode_pair(int p, int& it, int& jt) {
    int j = (int)((sqrtf(8.0f * (float)p + 1.0f) - 1.0f) * 0.5f);
    while ((j + 1) * (j + 2) / 2 <= p) ++j;
    while (j * (j + 1) / 2 > p) --j;
    jt = j;
    it = p - j * (j + 1) / 2;
}

// -- Kernel 0: row norms -> fp8 e4m3 normalized copy + norms + zero counters --
__global__ __launch_bounds__(256) void norm_kernel(const float* __restrict__ h,
                                                   unsigned char* __restrict__ hq,
                                                   float* __restrict__ norms,
                                                   int* __restrict__ gcnt,
                                                   int* __restrict__ gflag,
                                                   int* __restrict__ steal) {
    int row = blockIdx.x * 4 + (threadIdx.x >> 6);
    int lane = threadIdx.x & 63;
    if (blockIdx.x == 0 && threadIdx.x == 0) steal[0] = NBLK;  // stealing base
    const float4* hr4 = (const float4*)(h + (size_t)row * D);
    float4 p0 = hr4[lane], p1 = hr4[64 + lane];
    float ss = p0.x * p0.x + p0.y * p0.y + p0.z * p0.z + p0.w * p0.w +
               p1.x * p1.x + p1.y * p1.y + p1.z * p1.z + p1.w * p1.w;
#pragma unroll
    for (int off = 32; off > 0; off >>= 1) ss += __shfl_xor(ss, off, 64);
    float nrm = fmaxf(sqrtf(ss), EPS);
    float inv = 1.0f / nrm;
    if (lane == 0) { gcnt[row] = 0; gflag[row] = 0; norms[row] = nrm; }
    unsigned int w0 = __builtin_amdgcn_cvt_pk_fp8_f32(p0.x * inv, p0.y * inv, 0, false);
    w0 = __builtin_amdgcn_cvt_pk_fp8_f32(p0.z * inv, p0.w * inv, w0, true);
    unsigned int w1 = __builtin_amdgcn_cvt_pk_fp8_f32(p1.x * inv, p1.y * inv, 0, false);
    w1 = __builtin_amdgcn_cvt_pk_fp8_f32(p1.z * inv, p1.w * inv, w1, true);
    unsigned int* q32 = (unsigned int*)(hq + (size_t)row * D);
    q32[lane] = w0;
    q32[64 + lane] = w1;
}

// -- Kernel 1: SYMMETRIC fp8 MFMA sim, dynamic pair-stealing --
// First pair static (= blockIdx); next pair grabbed via atomicAdd(steal) at
// pair START (8 rounds of lead time; published to the block via the round
// barriers). Load imbalance drops from 3/2.03 pairs to ~2.3/2.03.
// Core round structure identical to R3/R4 (dbuf K64, vmcnt(4)).
__global__ __launch_bounds__(256, 4) void simfp8_kernel(
        const unsigned char* __restrict__ hq,
        unsigned int* __restrict__ gcand,
        int* __restrict__ gcnt,
        int* __restrict__ gflag,
        int* __restrict__ steal) {
    __shared__ unsigned char tiles[2][2][128 * 64];  // [sel][A/B] 32 KB
    __shared__ int cnt[256];                          // 1 KB
    __shared__ unsigned int lbuf[256][CAPL];          // 6 KB
    __shared__ int nextp_sh;

    const int b = blockIdx.x;
    const int t = threadIdx.x;
    const int wave = t >> 6, lane = t & 63;
    const int wr = (wave >> 1) * 64, wc = (wave & 1) * 64;
    const int lm32 = lane & 31, lg2 = lane >> 5;
    const int rk = (lm32 >> 2) & 3;  // read-side swizzle key ((row>>2)&3)

    // staging: chunk c = e*256 + t (e=0,1); row = e*64 + (t>>2), slot = t&3,
    // source chunk q = slot ^ ((row>>2)&3) = (t&3) ^ ((t>>4)&3)
    const int srow = t >> 2;
    const int sq = (t & 3) ^ ((t >> 4) & 3);

    cnt[t] = 0;   // ordered before first emit by the round barriers

    auto issue = [&](int ii0, int jj0, int r_) {
        int sel = r_ & 1;   // 8 rounds/pair (even) keeps dbuf parity global
        const unsigned char* gA = hq + (size_t)(ii0 + srow) * D + r_ * 64 + sq * 16;
        const unsigned char* gB = hq + (size_t)(jj0 + srow) * D + r_ * 64 + sq * 16;
        unsigned char* lA = &tiles[sel][0][t * 16];
        unsigned char* lB = &tiles[sel][1][t * 16];
#pragma unroll
        for (int e = 0; e < 2; e++) {
            load16(gA + (size_t)(e * 64) * D, lA + e * 4096);
            load16(gB + (size_t)(e * 64) * D, lB + e * 4096);
        }
    };

    int cit, cjt;
    decode_pair(b, cit, cjt);
    int ci0 = cit * 128, cj0 = cjt * 128;
    bool cdiag = (cit == cjt);
    issue(ci0, cj0, 0);

    f32x16 acc[2][2];
#pragma unroll
    for (int x = 0; x < 2; x++)
#pragma unroll
        for (int y = 0; y < 2; y++)
#pragma unroll
            for (int q = 0; q < 16; q++) acc[x][y][q] = 0.f;

    for (;;) {
        // grab next pair NOW (8 rounds of lead); barriers below publish it
        if (t == 0) nextp_sh = atomicAdd(steal, 1);

        int np = NPAIR, ni0 = 0, nj0 = 0;
        bool ndiag = false;

        for (int r = 0; r < 8; r++) {
            const int sel = r & 1;

            __builtin_amdgcn_s_barrier();   // prior reads of buffer sel done
            if (r < 7) {
                issue(ci0, cj0, r + 1);
                asm volatile("s_waitcnt vmcnt(4)" ::: "memory");  // drain round r
            } else {
                np = nextp_sh;   // published (>=2 barriers since write)
                if (np < NPAIR) {
                    int nit, njt;
                    decode_pair(np, nit, njt);
                    ni0 = nit * 128; nj0 = njt * 128; ndiag = (nit == njt);
                    issue(ni0, nj0, 0);          // prime next pair's round 0
                    asm volatile("s_waitcnt vmcnt(4)" ::: "memory");
                } else {
                    asm volatile("s_waitcnt vmcnt(0)" ::: "memory");
                }
            }
            __builtin_amdgcn_s_barrier();   // round r fully in LDS

#pragma unroll
            for (int kk = 0; kk < 4; kk++) {   // 4 x K16 fp8 MFMA steps = K64
                const int kb = ((kk ^ rk) << 4) + lg2 * 8;  // swizzled byte offset
                long long af[2], bfr[2];
#pragma unroll
                for (int x = 0; x < 2; x++)
                    af[x] = *(const long long*)&tiles[sel][0][(wr + x * 32 + lm32) * 64 + kb];
#pragma unroll
                for (int y = 0; y < 2; y++)
                    bfr[y] = *(const long long*)&tiles[sel][1][(wc + y * 32 + lm32) * 64 + kb];
#pragma unroll
                for (int x = 0; x < 2; x++)
#pragma unroll
                    for (int y = 0; y < 2; y++)
                        acc[x][y] = __builtin_amdgcn_mfma_f32_32x32x16_fp8_fp8(
                            af[x], bfr[y], acc[x][y], 0, 0, 0);
            }
        }

        // emit candidates to two-sided LDS buffer; reset acc for next pair.
        // 32x32 C/D: col = lane&31, row = (reg&3) + 8*(reg>>2) + 4*(lane>>5)
#pragma unroll
        for (int x = 0; x < 2; x++)
#pragma unroll
            for (int y = 0; y < 2; y++) {
                int lcol = wc + y * 32 + lm32;
                int gcol = cj0 + lcol;
#pragma unroll
                for (int q = 0; q < 16; q++) {
                    int rr = wr + x * 32 + (q & 3) + 8 * (q >> 2) + 4 * lg2;
                    int gi = ci0 + rr;
                    float v = acc[x][y][q];
                    acc[x][y][q] = 0.f;
                    if (gi == gcol) v = 1.0f;   // exact self-sim (diag pairs only)
                    if (v > TAU) {
                        unsigned int vb = bf16_bits_rne(v) << 16;
                        int idx = atomicAdd(&cnt[rr], 1);
                        if (idx < CAPL) lbuf[rr][idx] = vb | (unsigned int)gcol;
                        else {  // rare exact spill straight to global
                            int pg = atomicAdd(&gcnt[gi], 1);
                            if (pg < CAPG) gcand[(size_t)gi * CAPG + pg] = vb | (unsigned int)gcol;
                            else gflag[gi] = 1;
                        }
                        if (!cdiag) {   // mirrored entry for the j-side row
                            int idx2 = atomicAdd(&cnt[128 + lcol], 1);
                            if (idx2 < CAPL) lbuf[128 + lcol][idx2] = vb | (unsigned int)gi;
                            else {
                                int pg = atomicAdd(&gcnt[gcol], 1);
                                if (pg < CAPG) gcand[(size_t)gcol * CAPG + pg] = vb | (unsigned int)gi;
                                else gflag[gcol] = 1;
                            }
                        }
                    }
                }
            }

        __syncthreads();   // all emissions visible
        {
            int grow = (t < 128) ? (ci0 + t) : (cj0 + t - 128);
            int c = cnt[t];
            int s = c < CAPL ? c : CAPL;
            if (s > 0) {   // diag pairs: j-side cnt stays 0, auto-skipped
                int base = atomicAdd(&gcnt[grow], s);
                unsigned int* dst = gcand + (size_t)grow * CAPG;
                for (int k = 0; k < s; k++) {
                    int pp = base + k;
                    if (pp < CAPG) dst[pp] = lbuf[t][k];
                    else gflag[grow] = 1;
                }
            }
            cnt[t] = 0;   // owner-thread reset; next emit is 8 barriers away
        }

        if (np >= NPAIR) break;
        ci0 = ni0; cj0 = nj0;
        cdiag = ndiag;
        decode_pair(np, cit, cjt);   // cit/cjt kept consistent (cheap, uniform)
    }
}

// -- Kernel 2: exact top-12 + softmax + gather (fp8 neighbors, fp32 self) --
__global__ __launch_bounds__(256) void gather_kernel(const float* __restrict__ h,
                                                     const unsigned char* __restrict__ hq,
                                                     const float* __restrict__ norms,
                                                     const unsigned int* __restrict__ gcand,
                                                     const int* __restrict__ gcnt,
                                                     const int* __restrict__ gflag,
                                                     float* __restrict__ out) {
    int row = blockIdx.x * 4 + (threadIdx.x >> 6);
    int lane = threadIdx.x & 63;

    // early self-row prefetch: row is always its own top-1 (sim = 1.0)
    const float4* hr4 = (const float4*)(h + (size_t)row * D);
    float4 s0 = hr4[lane], s1 = hr4[64 + lane];

    int c = gcnt[row];

    float selv[K_TOP];
    int selj[K_TOP];

    if (c >= K_TOP && c <= CAPG && gflag[row] == 0) {
        const unsigned int* cr = gcand + (size_t)row * CAPG;
        unsigned int e[3];
#pragma unroll
        for (int q = 0; q < 3; q++) {
            int idx = lane + 64 * q;
            e[q] = (idx < c) ? cr[idx] : 0u;
        }
#pragma unroll
        for (int k = 0; k < K_TOP; k++) {
            unsigned int m = e[0];
            if (e[1] > m) m = e[1];
            if (e[2] > m) m = e[2];
#pragma unroll
            for (int off = 32; off > 0; off >>= 1) {
                unsigned int om = __shfl_xor(m, off, 64);
                if (om > m) m = om;
            }
            selv[k] = __uint_as_float(m & 0xFFFF0000u);
            selj[k] = (int)(m & 0x1FFFu);
#pragma unroll
            for (int q = 0; q < 3; q++)
                if (e[q] == m) e[q] = 0u;   // entries unique (distinct cols)
        }
    } else {
        // exact brute-force fallback over fp8 rows (rare; cheap insurance)
        float vals[K_TOP];
        int idxs[K_TOP];
#pragma unroll
        for (int q = 0; q < K_TOP; q++) { vals[q] = -3e38f; idxs[q] = 0; }
        float minv = -3e38f;
        int minp = 0;
        const unsigned int* rp = (const unsigned int*)(hq + (size_t)row * D);
        for (int col = lane; col < N; col += 64) {
            const unsigned int* cp = (const unsigned int*)(hq + (size_t)col * D);
            float s = 0.f;
            for (int k4 = 0; k4 < D / 4; k4++) {
                unsigned int ra = rp[k4], ca = cp[k4];
                s += __builtin_amdgcn_cvt_f32_fp8(ra, 0) * __builtin_amdgcn_cvt_f32_fp8(ca, 0);
                s += __builtin_amdgcn_cvt_f32_fp8(ra, 1) * __builtin_amdgcn_cvt_f32_fp8(ca, 1);
                s += __builtin_amdgcn_cvt_f32_fp8(ra, 2) * __builtin_amdgcn_cvt_f32_fp8(ca, 2);
                s += __builtin_amdgcn_cvt_f32_fp8(ra, 3) * __builtin_amdgcn_cvt_f32_fp8(ca, 3);
            }
            if (col == row) s = 1.0f;
            if (s > minv) {
                vals[minp] = s; idxs[minp] = col;
                minv = vals[0]; minp = 0;
#pragma unroll
                for (int q = 1; q < K_TOP; q++)
                    if (vals[q] < minv) { minv = vals[q]; minp = q; }
            }
        }
        for (int k = 0; k < K_TOP; k++) {
            float bv = vals[0]; int bp = 0;
#pragma unroll
            for (int q = 1; q < K_TOP; q++)
                if (vals[q] > bv) { bv = vals[q]; bp = q; }
            float v = bv; int j = idxs[bp]; int src = lane;
#pragma unroll
            for (int off = 32; off > 0; off >>= 1) {
                float ov = __shfl_xor(v, off, 64);
                int oj = __shfl_xor(j, off, 64);
                int os = __shfl_xor(src, off, 64);
                if (ov > v || (ov == v && os < src)) { v = ov; j = oj; src = os; }
            }
            selv[k] = __uint_as_float((unsigned int)(bf16_bits_rne(v) << 16));
            selj[k] = j;
            if (lane == src) vals[bp] = -3e38f;
        }
    }

    // batch-issue all neighbor fp8 row loads (12-deep MLP) + their norms
    unsigned int na[K_TOP], nb[K_TOP];
    float wn[K_TOP];
#pragma unroll
    for (int q = 0; q < K_TOP; q++) {
        const unsigned int* r32 = (const unsigned int*)(hq + (size_t)selj[q] * D);
        na[q] = r32[lane];
        nb[q] = r32[64 + lane];
        wn[q] = norms[selj[q]];
    }

    float mx = selv[0];
    float beta[K_TOP];
    float sum = 0.f;
#pragma unroll
    for (int q = 0; q < K_TOP; q++) { beta[q] = __expf(THETA * (selv[q] - mx)); sum += beta[q]; }
    float rs = 1.0f / sum;

    // lane owns output elems [lane*4,+4) and [256+lane*4,+4)
    float acc[8];
#pragma unroll
    for (int ee = 0; ee < 8; ee++) acc[ee] = 0.f;
#pragma unroll
    for (int q = 0; q < K_TOP; q++) {
        float w = beta[q] * rs;
        if (selj[q] == row) {   // wave-uniform; dominant term stays fp32-exact
            acc[0] += w * s0.x; acc[1] += w * s0.y; acc[2] += w * s0.z; acc[3] += w * s0.w;
            acc[4] += w * s1.x; acc[5] += w * s1.y; acc[6] += w * s1.z; acc[7] += w * s1.w;
        } else {                // neighbors (weight ~2e-4): fp8 row x norm
            float wj = w * wn[q];
            acc[0] += wj * __builtin_amdgcn_cvt_f32_fp8(na[q], 0);
            acc[1] += wj * __builtin_amdgcn_cvt_f32_fp8(na[q], 1);
            acc[2] += wj * __builtin_amdgcn_cvt_f32_fp8(na[q], 2);
            acc[3] += wj * __builtin_amdgcn_cvt_f32_fp8(na[q], 3);
            acc[4] += wj * __builtin_amdgcn_cvt_f32_fp8(nb[q], 0);
            acc[5] += wj * __builtin_amdgcn_cvt_f32_fp8(nb[q], 1);
            acc[6] += wj * __builtin_amdgcn_cvt_f32_fp8(nb[q], 2);
            acc[7] += wj * __builtin_amdgcn_cvt_f32_fp8(nb[q], 3);
        }
    }
    float4* o4 = (float4*)(out + (size_t)row * D);
    o4[lane] = make_float4(acc[0], acc[1], acc[2], acc[3]);
    o4[64 + lane] = make_float4(acc[4], acc[5], acc[6], acc[7]);
}

extern "C" void kernel_launch(void* const* d_in, const int* in_sizes, int n_in,
                              void* d_out, int out_size, void* d_ws, size_t ws_size,
                              hipStream_t stream) {
    const float* h = (const float*)d_in[0];
    float* out = (float*)d_out;

    char* ws = (char*)d_ws;
    unsigned char* hq = (unsigned char*)ws;                      // 4 MB fp8
    size_t off = (size_t)N * D;
    float* norms = (float*)(ws + off);                           // 32 KB
    int* gcnt = (int*)(ws + off + (size_t)N * 4);                // 32 KB
    int* gflag = (int*)(ws + off + (size_t)N * 8);               // 32 KB
    unsigned int* gcand = (unsigned int*)(ws + off + (size_t)N * 12);  // 6 MB
    int* steal = (int*)(ws + off + (size_t)N * 12 + (size_t)N * CAPG * 4);  // 4 B

    norm_kernel<<<N / 4, 256, 0, stream>>>(h, hq, norms, gcnt, gflag, steal);
    simfp8_kernel<<<NBLK, 256, 0, stream>>>(hq, gcand, gcnt, gflag, steal);
    gather_kernel<<<N / 4, 256, 0, stream>>>(h, hq, norms, gcand, gcnt, gflag, out);
}

// Round 9
// 142.102 us; speedup vs baseline: 3.9735x; 1.0162x over previous
//
#include <hip/hip_runtime.h>
#include <hip/hip_bf16.h>

#define N 8192
#define D 512
#define K_TOP 12
#define THETA 10.0f
#define EPS 1e-8f
#define TAU 0.10f      // candidate threshold; spill+fallback guarantee the guard
#define CAPL 6         // per-row per-pair LDS cap (overflow -> exact global spill)
#define CAPG 192       // per-row global candidate cap
#define NPAIR 2080     // 64*65/2 upper-triangular 128x128 tile pairs
#define NBLK 1024      // persistent blocks: exactly 4/CU, one generation

typedef float f32x16 __attribute__((ext_vector_type(16)));

__device__ __forceinline__ unsigned int bf16_bits_rne(float v) {
    unsigned int u = __float_as_uint(v);
    u += 0x7FFFu + ((u >> 16) & 1u);
    return u >> 16;
}

// async global->LDS DMA, 16B per lane; LDS dest is wave-uniform base + lane*16
__device__ __forceinline__ void load16(const unsigned char* g, unsigned char* l) {
    __builtin_amdgcn_global_load_lds(
        (const __attribute__((address_space(1))) unsigned int*)g,
        (__attribute__((address_space(3))) unsigned int*)l, 16, 0, 0);
}

// column-major (jt-major) triangle decode: p = jt*(jt+1)/2 + it, it in [0,jt]
__device__ __forceinline__ void decode_pair(int p, int& it, int& jt) {
    int j = (int)((sqrtf(8.0f * (float)p + 1.0f) - 1.0f) * 0.5f);
    while ((j + 1) * (j + 2) / 2 <= p) ++j;
    while (j * (j + 1) / 2 > p) --j;
    jt = j;
    it = p - j * (j + 1) / 2;
}

// -- Kernel 0: row norms -> fp8 e4m3 normalized copy + norms + zero counters --
__global__ __launch_bounds__(256) void norm_kernel(const float* __restrict__ h,
                                                   unsigned char* __restrict__ hq,
                                                   float* __restrict__ norms,
                                                   int* __restrict__ gcnt,
                                                   int* __restrict__ gflag) {
    int row = blockIdx.x * 4 + (threadIdx.x >> 6);
    int lane = threadIdx.x & 63;
    const float4* hr4 = (const float4*)(h + (size_t)row * D);
    float4 p0 = hr4[lane], p1 = hr4[64 + lane];
    float ss = p0.x * p0.x + p0.y * p0.y + p0.z * p0.z + p0.w * p0.w +
               p1.x * p1.x + p1.y * p1.y + p1.z * p1.z + p1.w * p1.w;
#pragma unroll
    for (int off = 32; off > 0; off >>= 1) ss += __shfl_xor(ss, off, 64);
    float nrm = fmaxf(sqrtf(ss), EPS);
    float inv = 1.0f / nrm;
    if (lane == 0) { gcnt[row] = 0; gflag[row] = 0; norms[row] = nrm; }
    unsigned int w0 = __builtin_amdgcn_cvt_pk_fp8_f32(p0.x * inv, p0.y * inv, 0, false);
    w0 = __builtin_amdgcn_cvt_pk_fp8_f32(p0.z * inv, p0.w * inv, w0, true);
    unsigned int w1 = __builtin_amdgcn_cvt_pk_fp8_f32(p1.x * inv, p1.y * inv, 0, false);
    w1 = __builtin_amdgcn_cvt_pk_fp8_f32(p1.z * inv, p1.w * inv, w1, true);
    unsigned int* q32 = (unsigned int*)(hq + (size_t)row * D);
    q32[lane] = w0;
    q32[64 + lane] = w1;
}

// -- Kernel 1: SYMMETRIC fp8 MFMA sim, 4-deep K32 sub-phase pipeline --
// Static pair schedule (b, b+1024, b+2048). Per pair: 16 bodies of K32.
// Body: issue loads for phase g+2 -> vmcnt(4) -> ONE barrier -> 8 MFMA.
// Loads get 2 bodies of lead (~2x HBM latency); vmcnt never drains to 0
// except the final body; prefetch crosses pair boundaries (bodies 14/15
// issue the next pair's phases 0/1; emit uses an lgkm-only barrier).
// Swizzle: 16B chunk c of row r at slot c ^ ((r>>2)&1) -> with the lg2*8
// sub-offset the b64 read covers all 32 banks = 4-phase structural floor.
__global__ __launch_bounds__(256, 4) void simfp8_kernel(
        const unsigned char* __restrict__ hq,
        unsigned int* __restrict__ gcand,
        int* __restrict__ gcnt,
        int* __restrict__ gflag) {
    __shared__ unsigned char tiles[4][2][128 * 32];  // 4-deep rotation, 32 KB
    __shared__ int cnt[256];                          // 1 KB
    __shared__ unsigned int lbuf[256][CAPL];          // 6 KB

    const int b = blockIdx.x;
    const int t = threadIdx.x;
    const int wave = t >> 6, lane = t & 63;
    const int wr = (wave >> 1) * 64, wc = (wave & 1) * 64;
    const int lm32 = lane & 31, lg2 = lane >> 5;
    const int rk1 = (lm32 >> 2) & 1;   // read-side swizzle key ((row>>2)&1)

    // staging: thread t stages 16B chunk: row = t>>1, slot = t&1,
    // source chunk q = slot ^ ((row>>2)&1) = (t&1) ^ ((t>>3)&1)
    const int srow = t >> 1;
    const int sq = (t & 1) ^ ((t >> 3) & 1);

    cnt[t] = 0;   // ordered before first emit by the body barriers

    auto issue_sub = [&](int ii0, int jj0, int ph) {
        const unsigned char* gA = hq + (size_t)(ii0 + srow) * D + ph * 32 + sq * 16;
        const unsigned char* gB = hq + (size_t)(jj0 + srow) * D + ph * 32 + sq * 16;
        load16(gA, &tiles[ph & 3][0][t * 16]);
        load16(gB, &tiles[ph & 3][1][t * 16]);
    };

    const int nloc = (b + 2048 < NPAIR) ? 3 : 2;   // blocks 0..31 take a 3rd pair
    const int T = nloc * 16;                        // total bodies

    int cit, cjt;
    decode_pair(b, cit, cjt);
    int ci0 = cit * 128, cj0 = cjt * 128;
    bool cdiag = (cit == cjt);
    int ni0 = 0, nj0 = 0;
    bool ndiag = false;
    if (nloc > 1) {
        int nit, njt;
        decode_pair(b + NBLK, nit, njt);
        ni0 = nit * 128; nj0 = njt * 128; ndiag = (nit == njt);
    }

    // prologue: phases 0 and 1 in flight
    issue_sub(ci0, cj0, 0);
    issue_sub(ci0, cj0, 1);

    f32x16 acc[2][2];
#pragma unroll
    for (int x = 0; x < 2; x++)
#pragma unroll
        for (int y = 0; y < 2; y++)
#pragma unroll
            for (int q = 0; q < 16; q++) acc[x][y][q] = 0.f;

    for (int qp = 0; qp < nloc; qp++) {
        for (int g = 0; g < 16; g++) {
            const int G = qp * 16 + g;

            if (G + 2 < T) {
                if (g < 14) issue_sub(ci0, cj0, g + 2);
                else        issue_sub(ni0, nj0, g - 14);  // next pair's 0/1
                asm volatile("s_waitcnt vmcnt(4)" ::: "memory");  // phase g landed (mine)
            } else if (G + 1 < T) {
                asm volatile("s_waitcnt vmcnt(2)" ::: "memory");
            } else {
                asm volatile("s_waitcnt vmcnt(0)" ::: "memory");
            }
            __builtin_amdgcn_s_barrier();   // everyone's phase-g loads landed

#pragma unroll
            for (int kk = 0; kk < 2; kk++) {   // 2 x K16 fp8 MFMA steps = K32
                const int kb = ((kk ^ rk1) << 4) + lg2 * 8;  // swizzled byte offset
                long long af[2], bfr[2];
#pragma unroll
                for (int x = 0; x < 2; x++)
                    af[x] = *(const long long*)&tiles[g & 3][0][(wr + x * 32 + lm32) * 32 + kb];
#pragma unroll
                for (int y = 0; y < 2; y++)
                    bfr[y] = *(const long long*)&tiles[g & 3][1][(wc + y * 32 + lm32) * 32 + kb];
#pragma unroll
                for (int x = 0; x < 2; x++)
#pragma unroll
                    for (int y = 0; y < 2; y++)
                        acc[x][y] = __builtin_amdgcn_mfma_f32_32x32x16_fp8_fp8(
                            af[x], bfr[y], acc[x][y], 0, 0, 0);
            }
        }

        // emit candidates to two-sided LDS buffer; reset acc for next pair.
        // 32x32 C/D: col = lane&31, row = (reg&3) + 8*(reg>>2) + 4*(lane>>5)
#pragma unroll
        for (int x = 0; x < 2; x++)
#pragma unroll
            for (int y = 0; y < 2; y++) {
                int lcol = wc + y * 32 + lm32;
                int gcol = cj0 + lcol;
#pragma unroll
                for (int q = 0; q < 16; q++) {
                    int rr = wr + x * 32 + (q & 3) + 8 * (q >> 2) + 4 * lg2;
                    int gi = ci0 + rr;
                    float v = acc[x][y][q];
                    acc[x][y][q] = 0.f;
                    if (gi == gcol) v = 1.0f;   // exact self-sim (diag pairs only)
                    if (v > TAU) {
                        unsigned int vb = bf16_bits_rne(v) << 16;
                        int idx = atomicAdd(&cnt[rr], 1);
                        if (idx < CAPL) lbuf[rr][idx] = vb | (unsigned int)gcol;
                        else {  // rare exact spill straight to global (over-waits
                                // a later vmcnt slightly; correctness unaffected)
                            int pg = atomicAdd(&gcnt[gi], 1);
                            if (pg < CAPG) gcand[(size_t)gi * CAPG + pg] = vb | (unsigned int)gcol;
                            else gflag[gi] = 1;
                        }
                        if (!cdiag) {   // mirrored entry for the j-side row
                            int idx2 = atomicAdd(&cnt[128 + lcol], 1);
                            if (idx2 < CAPL) lbuf[128 + lcol][idx2] = vb | (unsigned int)gi;
                            else {
                                int pg = atomicAdd(&gcnt[gcol], 1);
                                if (pg < CAPG) gcand[(size_t)gcol * CAPG + pg] = vb | (unsigned int)gi;
                                else gflag[gcol] = 1;
                            }
                        }
                    }
                }
            }

        // lgkm-only barrier: do NOT drain vmcnt (next pair's loads in flight)
        asm volatile("s_waitcnt lgkmcnt(0)" ::: "memory");
        __builtin_amdgcn_s_barrier();
        {
            int grow = (t < 128) ? (ci0 + t) : (cj0 + t - 128);
            int c = cnt[t];
            int s = c < CAPL ? c : CAPL;
            if (s > 0) {   // diag pairs: j-side cnt stays 0, auto-skipped
                int base = atomicAdd(&gcnt[grow], s);
                unsigned int* dst = gcand + (size_t)grow * CAPG;
                for (int k = 0; k < s; k++) {
                    int pp = base + k;
                    if (pp < CAPG) dst[pp] = lbuf[t][k];
                    else gflag[grow] = 1;
                }
            }
            cnt[t] = 0;   // owner-thread reset; next emit is >=16 barriers away
        }

        // rotate pair state; decode the pair after next (if any)
        ci0 = ni0; cj0 = nj0; cdiag = ndiag;
        if (qp + 2 < nloc) {
            int nit, njt;
            decode_pair(b + (qp + 2) * NBLK, nit, njt);
            ni0 = nit * 128; nj0 = njt * 128; ndiag = (nit == njt);
        }
    }
}

// -- Kernel 2: exact top-12 + softmax + gather (fp8 neighbors, fp32 self) --
__global__ __launch_bounds__(256) void gather_kernel(const float* __restrict__ h,
                                                     const unsigned char* __restrict__ hq,
                                                     const float* __restrict__ norms,
                                                     const unsigned int* __restrict__ gcand,
                                                     const int* __restrict__ gcnt,
                                                     const int* __restrict__ gflag,
                                                     float* __restrict__ out) {
    int row = blockIdx.x * 4 + (threadIdx.x >> 6);
    int lane = threadIdx.x & 63;

    // early self-row prefetch: row is always its own top-1 (sim = 1.0)
    const float4* hr4 = (const float4*)(h + (size_t)row * D);
    float4 s0 = hr4[lane], s1 = hr4[64 + lane];

    int c = gcnt[row];

    float selv[K_TOP];
    int selj[K_TOP];

    if (c >= K_TOP && c <= CAPG && gflag[row] == 0) {
        const unsigned int* cr = gcand + (size_t)row * CAPG;
        unsigned int e[3];
#pragma unroll
        for (int q = 0; q < 3; q++) {
            int idx = lane + 64 * q;
            e[q] = (idx < c) ? cr[idx] : 0u;
        }
#pragma unroll
        for (int k = 0; k < K_TOP; k++) {
            unsigned int m = e[0];
            if (e[1] > m) m = e[1];
            if (e[2] > m) m = e[2];
#pragma unroll
            for (int off = 32; off > 0; off >>= 1) {
                unsigned int om = __shfl_xor(m, off, 64);
                if (om > m) m = om;
            }
            selv[k] = __uint_as_float(m & 0xFFFF0000u);
            selj[k] = (int)(m & 0x1FFFu);
#pragma unroll
            for (int q = 0; q < 3; q++)
                if (e[q] == m) e[q] = 0u;   // entries unique (distinct cols)
        }
    } else {
        // exact brute-force fallback over fp8 rows (rare; cheap insurance)
        float vals[K_TOP];
        int idxs[K_TOP];
#pragma unroll
        for (int q = 0; q < K_TOP; q++) { vals[q] = -3e38f; idxs[q] = 0; }
        float minv = -3e38f;
        int minp = 0;
        const unsigned int* rp = (const unsigned int*)(hq + (size_t)row * D);
        for (int col = lane; col < N; col += 64) {
            const unsigned int* cp = (const unsigned int*)(hq + (size_t)col * D);
            float s = 0.f;
            for (int k4 = 0; k4 < D / 4; k4++) {
                unsigned int ra = rp[k4], ca = cp[k4];
                s += __builtin_amdgcn_cvt_f32_fp8(ra, 0) * __builtin_amdgcn_cvt_f32_fp8(ca, 0);
                s += __builtin_amdgcn_cvt_f32_fp8(ra, 1) * __builtin_amdgcn_cvt_f32_fp8(ca, 1);
                s += __builtin_amdgcn_cvt_f32_fp8(ra, 2) * __builtin_amdgcn_cvt_f32_fp8(ca, 2);
                s += __builtin_amdgcn_cvt_f32_fp8(ra, 3) * __builtin_amdgcn_cvt_f32_fp8(ca, 3);
            }
            if (col == row) s = 1.0f;
            if (s > minv) {
                vals[minp] = s; idxs[minp] = col;
                minv = vals[0]; minp = 0;
#pragma unroll
                for (int q = 1; q < K_TOP; q++)
                    if (vals[q] < minv) { minv = vals[q]; minp = q; }
            }
        }
        for (int k = 0; k < K_TOP; k++) {
            float bv = vals[0]; int bp = 0;
#pragma unroll
            for (int q = 1; q < K_TOP; q++)
                if (vals[q] > bv) { bv = vals[q]; bp = q; }
            float v = bv; int j = idxs[bp]; int src = lane;
#pragma unroll
            for (int off = 32; off > 0; off >>= 1) {
                float ov = __shfl_xor(v, off, 64);
                int oj = __shfl_xor(j, off, 64);
                int os = __shfl_xor(src, off, 64);
                if (ov > v || (ov == v && os < src)) { v = ov; j = oj; src = os; }
            }
            selv[k] = __uint_as_float((unsigned int)(bf16_bits_rne(v) << 16));
            selj[k] = j;
            if (lane == src) vals[bp] = -3e38f;
        }
    }

    // batch-issue all neighbor fp8 row loads (12-deep MLP) + their norms
    unsigned int na[K_TOP], nb[K_TOP];
    float wn[K_TOP];
#pragma unroll
    for (int q = 0; q < K_TOP; q++) {
        const unsigned int* r32 = (const unsigned int*)(hq + (size_t)selj[q] * D);
        na[q] = r32[lane];
        nb[q] = r32[64 + lane];
        wn[q] = norms[selj[q]];
    }

    float mx = selv[0];
    float beta[K_TOP];
    float sum = 0.f;
#pragma unroll
    for (int q = 0; q < K_TOP; q++) { beta[q] = __expf(THETA * (selv[q] - mx)); sum += beta[q]; }
    float rs = 1.0f / sum;

    // lane owns output elems [lane*4,+4) and [256+lane*4,+4)
    float acc[8];
#pragma unroll
    for (int ee = 0; ee < 8; ee++) acc[ee] = 0.f;
#pragma unroll
    for (int q = 0; q < K_TOP; q++) {
        float w = beta[q] * rs;
        if (selj[q] == row) {   // wave-uniform; dominant term stays fp32-exact
            acc[0] += w * s0.x; acc[1] += w * s0.y; acc[2] += w * s0.z; acc[3] += w * s0.w;
            acc[4] += w * s1.x; acc[5] += w * s1.y; acc[6] += w * s1.z; acc[7] += w * s1.w;
        } else {                // neighbors (weight ~2e-4): fp8 row x norm
            float wj = w * wn[q];
            acc[0] += wj * __builtin_amdgcn_cvt_f32_fp8(na[q], 0);
            acc[1] += wj * __builtin_amdgcn_cvt_f32_fp8(na[q], 1);
            acc[2] += wj * __builtin_amdgcn_cvt_f32_fp8(na[q], 2);
            acc[3] += wj * __builtin_amdgcn_cvt_f32_fp8(na[q], 3);
            acc[4] += wj * __builtin_amdgcn_cvt_f32_fp8(nb[q], 0);
            acc[5] += wj * __builtin_amdgcn_cvt_f32_fp8(nb[q], 1);
            acc[6] += wj * __builtin_amdgcn_cvt_f32_fp8(nb[q], 2);
            acc[7] += wj * __builtin_amdgcn_cvt_f32_fp8(nb[q], 3);
        }
    }
    float4* o4 = (float4*)(out + (size_t)row * D);
    o4[lane] = make_float4(acc[0], acc[1], acc[2], acc[3]);
    o4[64 + lane] = make_float4(acc[4], acc[5], acc[6], acc[7]);
}

extern "C" void kernel_launch(void* const* d_in, const int* in_sizes, int n_in,
                              void* d_out, int out_size, void* d_ws, size_t ws_size,
                              hipStream_t stream) {
    const float* h = (const float*)d_in[0];
    float* out = (float*)d_out;

    char* ws = (char*)d_ws;
    unsigned char* hq = (unsigned char*)ws;                      // 4 MB fp8
    size_t off = (size_t)N * D;
    float* norms = (float*)(ws + off);                           // 32 KB
    int* gcnt = (int*)(ws + off + (size_t)N * 4);                // 32 KB
    int* gflag = (int*)(ws + off + (size_t)N * 8);               // 32 KB
    unsigned int* gcand = (unsigned int*)(ws + off + (size_t)N * 12);  // 6 MB

    norm_kernel<<<N / 4, 256, 0, stream>>>(h, hq, norms, gcnt, gflag);
    simfp8_kernel<<<NBLK, 256, 0, stream>>>(hq, gcand, gcnt, gflag);
    gather_kernel<<<N / 4, 256, 0, stream>>>(h, hq, norms, gcand, gcnt, gflag, out);
}

// Round 10
// 130.764 us; speedup vs baseline: 4.3180x; 1.0867x over previous
//
#include <hip/hip_runtime.h>
#include <hip/hip_bf16.h>

#define N 8192
#define D 512
#define K_TOP 12
#define THETA 10.0f
#define EPS 1e-8f
#define TAU 0.10f      // candidate threshold; spill+fallback guarantee the guard
#define CAPL 6         // per-row per-pair LDS cap (overflow -> exact global spill)
#define CAPG 192       // per-row global candidate cap
#define NPAIR 2080     // 64*65/2 upper-triangular 128x128 tile pairs
#define NBLK 1024      // persistent blocks: exactly 4/CU, one generation

typedef float f32x16 __attribute__((ext_vector_type(16)));

__device__ __forceinline__ unsigned int bf16_bits_rne(float v) {
    unsigned int u = __float_as_uint(v);
    u += 0x7FFFu + ((u >> 16) & 1u);
    return u >> 16;
}

// async global->LDS DMA, 16B per lane; LDS dest is wave-uniform base + lane*16
__device__ __forceinline__ void load16(const unsigned char* g, unsigned char* l) {
    __builtin_amdgcn_global_load_lds(
        (const __attribute__((address_space(1))) unsigned int*)g,
        (__attribute__((address_space(3))) unsigned int*)l, 16, 0, 0);
}

// column-major (jt-major) triangle decode: p = jt*(jt+1)/2 + it, it in [0,jt]
__device__ __forceinline__ void decode_pair(int p, int& it, int& jt) {
    int j = (int)((sqrtf(8.0f * (float)p + 1.0f) - 1.0f) * 0.5f);
    while ((j + 1) * (j + 2) / 2 <= p) ++j;
    while (j * (j + 1) / 2 > p) --j;
    jt = j;
    it = p - j * (j + 1) / 2;
}

// -- Kernel 0: row norms -> fp8 e4m3 normalized copy + norms + zero counters --
__global__ __launch_bounds__(256) void norm_kernel(const float* __restrict__ h,
                                                   unsigned char* __restrict__ hq,
                                                   float* __restrict__ norms,
                                                   int* __restrict__ gcnt,
                                                   int* __restrict__ gflag) {
    int row = blockIdx.x * 4 + (threadIdx.x >> 6);
    int lane = threadIdx.x & 63;
    const float4* hr4 = (const float4*)(h + (size_t)row * D);
    float4 p0 = hr4[lane], p1 = hr4[64 + lane];
    float ss = p0.x * p0.x + p0.y * p0.y + p0.z * p0.z + p0.w * p0.w +
               p1.x * p1.x + p1.y * p1.y + p1.z * p1.z + p1.w * p1.w;
#pragma unroll
    for (int off = 32; off > 0; off >>= 1) ss += __shfl_xor(ss, off, 64);
    float nrm = fmaxf(sqrtf(ss), EPS);
    float inv = 1.0f / nrm;
    if (lane == 0) { gcnt[row] = 0; gflag[row] = 0; norms[row] = nrm; }
    unsigned int w0 = __builtin_amdgcn_cvt_pk_fp8_f32(p0.x * inv, p0.y * inv, 0, false);
    w0 = __builtin_amdgcn_cvt_pk_fp8_f32(p0.z * inv, p0.w * inv, w0, true);
    unsigned int w1 = __builtin_amdgcn_cvt_pk_fp8_f32(p1.x * inv, p1.y * inv, 0, false);
    w1 = __builtin_amdgcn_cvt_pk_fp8_f32(p1.z * inv, p1.w * inv, w1, true);
    unsigned int* q32 = (unsigned int*)(hq + (size_t)row * D);
    q32[lane] = w0;
    q32[64 + lane] = w1;
}

// -- Kernel 1: SYMMETRIC fp8 MFMA sim (R4 structure) + tail-strip pass --
// Main: every block does exactly 2 pairs (p = b, b+1024 -> covers 0..2047).
// Tail: the 32 remaining pairs (jt=63 column, it 32..63) split into 64
// half-width strips (128 rows x 64 cols, full K) run by blocks b<64.
// Wall: 3*T_pair -> 2*T_pair + ~0.55*T_pair.
__global__ __launch_bounds__(256, 4) void simfp8_kernel(
        const unsigned char* __restrict__ hq,
        unsigned int* __restrict__ gcand,
        int* __restrict__ gcnt,
        int* __restrict__ gflag) {
    __shared__ unsigned char tiles[2][2][128 * 64];  // [sel][A/B] 32 KB
    __shared__ int cnt[256];                          // 1 KB
    __shared__ unsigned int lbuf[256][CAPL];          // 6 KB

    const int b = blockIdx.x;
    const int t = threadIdx.x;
    const int wave = t >> 6, lane = t & 63;
    const int wr = (wave >> 1) * 64, wc = (wave & 1) * 64;
    const int lm32 = lane & 31, lg2 = lane >> 5;
    const int rk = (lm32 >> 2) & 3;  // read-side swizzle key ((row>>2)&3)

    // staging: chunk c = e*256 + t (e=0,1); row = e*64 + (t>>2), slot = t&3,
    // source chunk q = slot ^ ((row>>2)&3) = (t&3) ^ ((t>>4)&3)
    const int srow = t >> 2;
    const int sq = (t & 3) ^ ((t >> 4) & 3);

    // strip geometry (blocks b<64): pair p = 2048 + (b>>1), half (b&1)
    const int i0s = (32 + (b >> 1)) * 128;
    const int j0s = 63 * 128 + (b & 1) * 64;
    const bool sdiag = ((b >> 1) == 31);   // strip lies in diag tile (63,63)

    cnt[t] = 0;   // ordered before first emit by the round barriers

    auto issue = [&](int ii0, int jj0, int r_) {
        int sel = r_ & 1;   // 8 rounds/pair (even) keeps dbuf parity global
        const unsigned char* gA = hq + (size_t)(ii0 + srow) * D + r_ * 64 + sq * 16;
        const unsigned char* gB = hq + (size_t)(jj0 + srow) * D + r_ * 64 + sq * 16;
        unsigned char* lA = &tiles[sel][0][t * 16];
        unsigned char* lB = &tiles[sel][1][t * 16];
#pragma unroll
        for (int e = 0; e < 2; e++) {
            load16(gA + (size_t)(e * 64) * D, lA + e * 4096);
            load16(gB + (size_t)(e * 64) * D, lB + e * 4096);
        }
    };

    // strip staging: A full 128 rows (2 load16), B 64 rows (1 load16, all thr)
    auto issue_strip = [&](int r_) {
        int sel = r_ & 1;
        const unsigned char* gA = hq + (size_t)(i0s + srow) * D + r_ * 64 + sq * 16;
        const unsigned char* gB = hq + (size_t)(j0s + srow) * D + r_ * 64 + sq * 16;
        unsigned char* lA = &tiles[sel][0][t * 16];
#pragma unroll
        for (int e = 0; e < 2; e++)
            load16(gA + (size_t)(e * 64) * D, lA + e * 4096);
        load16(gB, &tiles[sel][1][t * 16]);   // rows 0..63 (4 KB used)
    };

    int cit, cjt;
    decode_pair(b, cit, cjt);
    int ci0 = cit * 128, cj0 = cjt * 128;
    bool cdiag = (cit == cjt);
    int ni0 = 0, nj0 = 0;
    bool ndiag = false;
    {
        int nit, njt;
        decode_pair(b + NBLK, nit, njt);
        ni0 = nit * 128; nj0 = njt * 128; ndiag = (nit == njt);
    }
    issue(ci0, cj0, 0);

    f32x16 acc[2][2];
#pragma unroll
    for (int x = 0; x < 2; x++)
#pragma unroll
        for (int y = 0; y < 2; y++)
#pragma unroll
            for (int q = 0; q < 16; q++) acc[x][y][q] = 0.f;

    for (int qp = 0; qp < 2; qp++) {
        for (int r = 0; r < 8; r++) {
            const int sel = r & 1;

            __builtin_amdgcn_s_barrier();   // prior reads of buffer sel done
            if (r < 7) {
                issue(ci0, cj0, r + 1);
                asm volatile("s_waitcnt vmcnt(4)" ::: "memory");  // drain round r
            } else if (qp == 0) {
                issue(ni0, nj0, 0);          // prime next pair's round 0
                asm volatile("s_waitcnt vmcnt(4)" ::: "memory");
            } else if (b < 64) {
                issue_strip(0);              // prime strip round 0 (3 loads)
                asm volatile("s_waitcnt vmcnt(3)" ::: "memory");
            } else {
                asm volatile("s_waitcnt vmcnt(0)" ::: "memory");
            }
            __builtin_amdgcn_s_barrier();   // round r fully in LDS

#pragma unroll
            for (int kk = 0; kk < 4; kk++) {   // 4 x K16 fp8 MFMA steps = K64
                const int kb = ((kk ^ rk) << 4) + lg2 * 8;  // swizzled byte offset
                long long af[2], bfr[2];
#pragma unroll
                for (int x = 0; x < 2; x++)
                    af[x] = *(const long long*)&tiles[sel][0][(wr + x * 32 + lm32) * 64 + kb];
#pragma unroll
                for (int y = 0; y < 2; y++)
                    bfr[y] = *(const long long*)&tiles[sel][1][(wc + y * 32 + lm32) * 64 + kb];
#pragma unroll
                for (int x = 0; x < 2; x++)
#pragma unroll
                    for (int y = 0; y < 2; y++)
                        acc[x][y] = __builtin_amdgcn_mfma_f32_32x32x16_fp8_fp8(
                            af[x], bfr[y], acc[x][y], 0, 0, 0);
            }
        }

        // emit candidates to two-sided LDS buffer; reset acc for next pair.
        // 32x32 C/D: col = lane&31, row = (reg&3) + 8*(reg>>2) + 4*(lane>>5)
#pragma unroll
        for (int x = 0; x < 2; x++)
#pragma unroll
            for (int y = 0; y < 2; y++) {
                int lcol = wc + y * 32 + lm32;
                int gcol = cj0 + lcol;
#pragma unroll
                for (int q = 0; q < 16; q++) {
                    int rr = wr + x * 32 + (q & 3) + 8 * (q >> 2) + 4 * lg2;
                    int gi = ci0 + rr;
                    float v = acc[x][y][q];
                    acc[x][y][q] = 0.f;
                    if (gi == gcol) v = 1.0f;   // exact self-sim (diag pairs only)
                    if (v > TAU) {
                        unsigned int vb = bf16_bits_rne(v) << 16;
                        int idx = atomicAdd(&cnt[rr], 1);
                        if (idx < CAPL) lbuf[rr][idx] = vb | (unsigned int)gcol;
                        else {  // rare exact spill straight to global
                            int pg = atomicAdd(&gcnt[gi], 1);
                            if (pg < CAPG) gcand[(size_t)gi * CAPG + pg] = vb | (unsigned int)gcol;
                            else gflag[gi] = 1;
                        }
                        if (!cdiag) {   // mirrored entry for the j-side row
                            int idx2 = atomicAdd(&cnt[128 + lcol], 1);
                            if (idx2 < CAPL) lbuf[128 + lcol][idx2] = vb | (unsigned int)gi;
                            else {
                                int pg = atomicAdd(&gcnt[gcol], 1);
                                if (pg < CAPG) gcand[(size_t)gcol * CAPG + pg] = vb | (unsigned int)gi;
                                else gflag[gcol] = 1;
                            }
                        }
                    }
                }
            }

        __syncthreads();   // all emissions visible
        {
            int grow = (t < 128) ? (ci0 + t) : (cj0 + t - 128);
            int c = cnt[t];
            int s = c < CAPL ? c : CAPL;
            if (s > 0) {   // diag pairs: j-side cnt stays 0, auto-skipped
                int base = atomicAdd(&gcnt[grow], s);
                unsigned int* dst = gcand + (size_t)grow * CAPG;
                for (int k = 0; k < s; k++) {
                    int pp = base + k;
                    if (pp < CAPG) dst[pp] = lbuf[t][k];
                    else gflag[grow] = 1;
                }
            }
            cnt[t] = 0;   // owner-thread reset; next emit is 8 barriers away
        }

        ci0 = ni0; cj0 = nj0; cdiag = ndiag;
    }

    if (b >= 64) return;

    // ===== strip pass: 128 x 64 strip of pair p = 2048+(b>>1), full K ========
    // Wave w computes rows [w*32, w*32+32) x the strip's 64 cols: 2 acc.
    {
        const int wr2 = wave * 32;
        f32x16 sacc[2];
#pragma unroll
        for (int y = 0; y < 2; y++)
#pragma unroll
            for (int q = 0; q < 16; q++) sacc[y][q] = 0.f;

        for (int r = 0; r < 8; r++) {
            const int sel = r & 1;

            __builtin_amdgcn_s_barrier();
            if (r < 7) {
                issue_strip(r + 1);
                asm volatile("s_waitcnt vmcnt(3)" ::: "memory");  // drain round r
            } else {
                asm volatile("s_waitcnt vmcnt(0)" ::: "memory");
            }
            __builtin_amdgcn_s_barrier();

#pragma unroll
            for (int kk = 0; kk < 4; kk++) {
                const int kb = ((kk ^ rk) << 4) + lg2 * 8;
                long long af =
                    *(const long long*)&tiles[sel][0][(wr2 + lm32) * 64 + kb];
                long long bfr[2];
#pragma unroll
                for (int y = 0; y < 2; y++)
                    bfr[y] = *(const long long*)&tiles[sel][1][(y * 32 + lm32) * 64 + kb];
#pragma unroll
                for (int y = 0; y < 2; y++)
                    sacc[y] = __builtin_amdgcn_mfma_f32_32x32x16_fp8_fp8(
                        af, bfr[y], sacc[y], 0, 0, 0);
            }
        }

        // emit: i-side rows 0..127 -> cnt[rr]; j-side strip cols -> cnt[128+lcol]
#pragma unroll
        for (int y = 0; y < 2; y++) {
            int lcol = y * 32 + lm32;            // 0..63 within strip
            int gcol = j0s + lcol;
#pragma unroll
            for (int q = 0; q < 16; q++) {
                int rr = wr2 + (q & 3) + 8 * (q >> 2) + 4 * lg2;
                int gi = i0s + rr;
                float v = sacc[y][q];
                if (gi == gcol) v = 1.0f;        // diag-tile strips only
                if (v > TAU) {
                    unsigned int vb = bf16_bits_rne(v) << 16;
                    int idx = atomicAdd(&cnt[rr], 1);
                    if (idx < CAPL) lbuf[rr][idx] = vb | (unsigned int)gcol;
                    else {
                        int pg = atomicAdd(&gcnt[gi], 1);
                        if (pg < CAPG) gcand[(size_t)gi * CAPG + pg] = vb | (unsigned int)gcol;
                        else gflag[gi] = 1;
                    }
                    if (!sdiag) {
                        int idx2 = atomicAdd(&cnt[128 + lcol], 1);
                        if (idx2 < CAPL) lbuf[128 + lcol][idx2] = vb | (unsigned int)gi;
                        else {
                            int pg = atomicAdd(&gcnt[gcol], 1);
                            if (pg < CAPG) gcand[(size_t)gcol * CAPG + pg] = vb | (unsigned int)gi;
                            else gflag[gcol] = 1;
                        }
                    }
                }
            }
        }

        __syncthreads();
        if (t < 192) {   // 128 i-rows + 64 j-cols
            int grow = (t < 128) ? (i0s + t) : (j0s + t - 128);
            int c = cnt[t];
            int s = c < CAPL ? c : CAPL;
            if (s > 0) {
                int base = atomicAdd(&gcnt[grow], s);
                unsigned int* dst = gcand + (size_t)grow * CAPG;
                for (int k = 0; k < s; k++) {
                    int pp = base + k;
                    if (pp < CAPG) dst[pp] = lbuf[t][k];
                    else gflag[grow] = 1;
                }
            }
        }
    }
}

// -- Kernel 2: exact top-12 + softmax + gather (fp8 neighbors, fp32 self) --
__global__ __launch_bounds__(256) void gather_kernel(const float* __restrict__ h,
                                                     const unsigned char* __restrict__ hq,
                                                     const float* __restrict__ norms,
                                                     const unsigned int* __restrict__ gcand,
                                                     const int* __restrict__ gcnt,
                                                     const int* __restrict__ gflag,
                                                     float* __restrict__ out) {
    int row = blockIdx.x * 4 + (threadIdx.x >> 6);
    int lane = threadIdx.x & 63;

    // early self-row prefetch: row is always its own top-1 (sim = 1.0)
    const float4* hr4 = (const float4*)(h + (size_t)row * D);
    float4 s0 = hr4[lane], s1 = hr4[64 + lane];

    int c = gcnt[row];

    float selv[K_TOP];
    int selj[K_TOP];

    if (c >= K_TOP && c <= CAPG && gflag[row] == 0) {
        const unsigned int* cr = gcand + (size_t)row * CAPG;
        unsigned int e[3];
#pragma unroll
        for (int q = 0; q < 3; q++) {
            int idx = lane + 64 * q;
            e[q] = (idx < c) ? cr[idx] : 0u;
        }
#pragma unroll
        for (int k = 0; k < K_TOP; k++) {
            unsigned int m = e[0];
            if (e[1] > m) m = e[1];
            if (e[2] > m) m = e[2];
#pragma unroll
            for (int off = 32; off > 0; off >>= 1) {
                unsigned int om = __shfl_xor(m, off, 64);
                if (om > m) m = om;
            }
            selv[k] = __uint_as_float(m & 0xFFFF0000u);
            selj[k] = (int)(m & 0x1FFFu);
#pragma unroll
            for (int q = 0; q < 3; q++)
                if (e[q] == m) e[q] = 0u;   // entries unique (distinct cols)
        }
    } else {
        // exact brute-force fallback over fp8 rows (rare; cheap insurance)
        float vals[K_TOP];
        int idxs[K_TOP];
#pragma unroll
        for (int q = 0; q < K_TOP; q++) { vals[q] = -3e38f; idxs[q] = 0; }
        float minv = -3e38f;
        int minp = 0;
        const unsigned int* rp = (const unsigned int*)(hq + (size_t)row * D);
        for (int col = lane; col < N; col += 64) {
            const unsigned int* cp = (const unsigned int*)(hq + (size_t)col * D);
            float s = 0.f;
            for (int k4 = 0; k4 < D / 4; k4++) {
                unsigned int ra = rp[k4], ca = cp[k4];
                s += __builtin_amdgcn_cvt_f32_fp8(ra, 0) * __builtin_amdgcn_cvt_f32_fp8(ca, 0);
                s += __builtin_amdgcn_cvt_f32_fp8(ra, 1) * __builtin_amdgcn_cvt_f32_fp8(ca, 1);
                s += __builtin_amdgcn_cvt_f32_fp8(ra, 2) * __builtin_amdgcn_cvt_f32_fp8(ca, 2);
                s += __builtin_amdgcn_cvt_f32_fp8(ra, 3) * __builtin_amdgcn_cvt_f32_fp8(ca, 3);
            }
            if (col == row) s = 1.0f;
            if (s > minv) {
                vals[minp] = s; idxs[minp] = col;
                minv = vals[0]; minp = 0;
#pragma unroll
                for (int q = 1; q < K_TOP; q++)
                    if (vals[q] < minv) { minv = vals[q]; minp = q; }
            }
        }
        for (int k = 0; k < K_TOP; k++) {
            float bv = vals[0]; int bp = 0;
#pragma unroll
            for (int q = 1; q < K_TOP; q++)
                if (vals[q] > bv) { bv = vals[q]; bp = q; }
            float v = bv; int j = idxs[bp]; int src = lane;
#pragma unroll
            for (int off = 32; off > 0; off >>= 1) {
                float ov = __shfl_xor(v, off, 64);
                int oj = __shfl_xor(j, off, 64);
                int os = __shfl_xor(src, off, 64);
                if (ov > v || (ov == v && os < src)) { v = ov; j = oj; src = os; }
            }
            selv[k] = __uint_as_float((unsigned int)(bf16_bits_rne(v) << 16));
            selj[k] = j;
            if (lane == src) vals[bp] = -3e38f;
        }
    }

    // batch-issue all neighbor fp8 row loads (12-deep MLP) + their norms
    unsigned int na[K_TOP], nb[K_TOP];
    float wn[K_TOP];
#pragma unroll
    for (int q = 0; q < K_TOP; q++) {
        const unsigned int* r32 = (const unsigned int*)(hq + (size_t)selj[q] * D);
        na[q] = r32[lane];
        nb[q] = r32[64 + lane];
        wn[q] = norms[selj[q]];
    }

    float mx = selv[0];
    float beta[K_TOP];
    float sum = 0.f;
#pragma unroll
    for (int q = 0; q < K_TOP; q++) { beta[q] = __expf(THETA * (selv[q] - mx)); sum += beta[q]; }
    float rs = 1.0f / sum;

    // lane owns output elems [lane*4,+4) and [256+lane*4,+4)
    float acc[8];
#pragma unroll
    for (int ee = 0; ee < 8; ee++) acc[ee] = 0.f;
#pragma unroll
    for (int q = 0; q < K_TOP; q++) {
        float w = beta[q] * rs;
        if (selj[q] == row) {   // wave-uniform; dominant term stays fp32-exact
            acc[0] += w * s0.x; acc[1] += w * s0.y; acc[2] += w * s0.z; acc[3] += w * s0.w;
            acc[4] += w * s1.x; acc[5] += w * s1.y; acc[6] += w * s1.z; acc[7] += w * s1.w;
        } else {                // neighbors (weight ~2e-4): fp8 row x norm
            float wj = w * wn[q];
            acc[0] += wj * __builtin_amdgcn_cvt_f32_fp8(na[q], 0);
            acc[1] += wj * __builtin_amdgcn_cvt_f32_fp8(na[q], 1);
            acc[2] += wj * __builtin_amdgcn_cvt_f32_fp8(na[q], 2);
            acc[3] += wj * __builtin_amdgcn_cvt_f32_fp8(na[q], 3);
            acc[4] += wj * __builtin_amdgcn_cvt_f32_fp8(nb[q], 0);
            acc[5] += wj * __builtin_amdgcn_cvt_f32_fp8(nb[q], 1);
            acc[6] += wj * __builtin_amdgcn_cvt_f32_fp8(nb[q], 2);
            acc[7] += wj * __builtin_amdgcn_cvt_f32_fp8(nb[q], 3);
        }
    }
    float4* o4 = (float4*)(out + (size_t)row * D);
    o4[lane] = make_float4(acc[0], acc[1], acc[2], acc[3]);
    o4[64 + lane] = make_float4(acc[4], acc[5], acc[6], acc[7]);
}

extern "C" void kernel_launch(void* const* d_in, const int* in_sizes, int n_in,
                              void* d_out, int out_size, void* d_ws, size_t ws_size,
                              hipStream_t stream) {
    const float* h = (const float*)d_in[0];
    float* out = (float*)d_out;

    char* ws = (char*)d_ws;
    unsigned char* hq = (unsigned char*)ws;                      // 4 MB fp8
    size_t off = (size_t)N * D;
    float* norms = (float*)(ws + off);                           // 32 KB
    int* gcnt = (int*)(ws + off + (size_t)N * 4);                // 32 KB
    int* gflag = (int*)(ws + off + (size_t)N * 8);               // 32 KB
    unsigned int* gcand = (unsigned int*)(ws + off + (size_t)N * 12);  // 6 MB

    norm_kernel<<<N / 4, 256, 0, stream>>>(h, hq, norms, gcnt, gflag);
    simfp8_kernel<<<NBLK, 256, 0, stream>>>(hq, gcand, gcnt, gflag);
    gather_kernel<<<N / 4, 256, 0, stream>>>(h, hq, norms, gcand, gcnt, gflag, out);
}

// Round 11
// 125.666 us; speedup vs baseline: 4.4932x; 1.0406x over previous
//
#include <hip/hip_runtime.h>
#include <hip/hip_bf16.h>

#define N 8192
#define D 512
#define K_TOP 12
#define THETA 10.0f
#define EPS 1e-8f
#define TAU 0.10f      // candidate threshold; spill+fallback guarantee the guard
#define CAPL 6         // per-row per-pair LDS cap (overflow -> exact global spill)
#define CAPG 192       // per-row global candidate cap
#define NPAIR 2080     // 64*65/2 upper-triangular 128x128 tile pairs
#define NBLK 1024      // persistent blocks: exactly 4/CU, one generation
#define INVQ2 (1.0f / 16129.0f)   // 1/127^2: i32 dot -> cosine sim

typedef int i32x4 __attribute__((ext_vector_type(4)));
typedef int i32x16 __attribute__((ext_vector_type(16)));

__device__ __forceinline__ unsigned int bf16_bits_rne(float v) {
    unsigned int u = __float_as_uint(v);
    u += 0x7FFFu + ((u >> 16) & 1u);
    return u >> 16;
}

// signed byte idx (0..3) of packed word
__device__ __forceinline__ int sb(unsigned int u, int idx) {
    return ((int)(u << (24 - 8 * idx))) >> 24;
}

// async global->LDS DMA, 16B per lane; LDS dest is wave-uniform base + lane*16
__device__ __forceinline__ void load16(const unsigned char* g, unsigned char* l) {
    __builtin_amdgcn_global_load_lds(
        (const __attribute__((address_space(1))) unsigned int*)g,
        (__attribute__((address_space(3))) unsigned int*)l, 16, 0, 0);
}

// column-major (jt-major) triangle decode: p = jt*(jt+1)/2 + it, it in [0,jt]
__device__ __forceinline__ void decode_pair(int p, int& it, int& jt) {
    int j = (int)((sqrtf(8.0f * (float)p + 1.0f) - 1.0f) * 0.5f);
    while ((j + 1) * (j + 2) / 2 <= p) ++j;
    while (j * (j + 1) / 2 > p) --j;
    jt = j;
    it = p - j * (j + 1) / 2;
}

// -- Kernel 0: row norms -> i8 (x127) normalized copy + norms + zero counters --
__global__ __launch_bounds__(256) void norm_kernel(const float* __restrict__ h,
                                                   unsigned char* __restrict__ hq,
                                                   float* __restrict__ norms,
                                                   int* __restrict__ gcnt,
                                                   int* __restrict__ gflag) {
    int row = blockIdx.x * 4 + (threadIdx.x >> 6);
    int lane = threadIdx.x & 63;
    const float4* hr4 = (const float4*)(h + (size_t)row * D);
    float4 p0 = hr4[lane], p1 = hr4[64 + lane];
    float ss = p0.x * p0.x + p0.y * p0.y + p0.z * p0.z + p0.w * p0.w +
               p1.x * p1.x + p1.y * p1.y + p1.z * p1.z + p1.w * p1.w;
#pragma unroll
    for (int off = 32; off > 0; off >>= 1) ss += __shfl_xor(ss, off, 64);
    float nrm = fmaxf(sqrtf(ss), EPS);
    float inv = 127.0f / nrm;   // |x|/nrm <= 1 -> quant in [-127,127], no clamp
    if (lane == 0) { gcnt[row] = 0; gflag[row] = 0; norms[row] = nrm; }
    int a0 = __float2int_rn(p0.x * inv), a1 = __float2int_rn(p0.y * inv);
    int a2 = __float2int_rn(p0.z * inv), a3 = __float2int_rn(p0.w * inv);
    int b0 = __float2int_rn(p1.x * inv), b1 = __float2int_rn(p1.y * inv);
    int b2 = __float2int_rn(p1.z * inv), b3 = __float2int_rn(p1.w * inv);
    unsigned int w0 = (a0 & 255) | ((a1 & 255) << 8) | ((a2 & 255) << 16) | ((a3 & 255) << 24);
    unsigned int w1 = (b0 & 255) | ((b1 & 255) << 8) | ((b2 & 255) << 16) | ((b3 & 255) << 24);
    unsigned int* q32 = (unsigned int*)(hq + (size_t)row * D);
    q32[lane] = w0;
    q32[64 + lane] = w1;
}

// -- Kernel 1: SYMMETRIC i8 MFMA sim (R10 structure, mfma_i32_32x32x32_i8) --
// Same byte layout/staging/swizzle as the fp8 version (K64 round = 64 B/row);
// fragment reads are b128 (one 16B chunk = lane's K-half of slab kk), MFMA
// count halves (8/round), i8 rate is 2x fp8 -> MFMA-pipe time halves.
// Main: every block does exactly 2 pairs; tail: 32 pairs as 64 half-strips.
__global__ __launch_bounds__(256, 4) void simfp8_kernel(
        const unsigned char* __restrict__ hq,
        unsigned int* __restrict__ gcand,
        int* __restrict__ gcnt,
        int* __restrict__ gflag) {
    __shared__ unsigned char tiles[2][2][128 * 64];  // [sel][A/B] 32 KB
    __shared__ int cnt[256];                          // 1 KB
    __shared__ unsigned int lbuf[256][CAPL];          // 6 KB

    const int b = blockIdx.x;
    const int t = threadIdx.x;
    const int wave = t >> 6, lane = t & 63;
    const int wr = (wave >> 1) * 64, wc = (wave & 1) * 64;
    const int lm32 = lane & 31, lg2 = lane >> 5;
    const int rk = (lm32 >> 2) & 3;  // read-side swizzle key ((row>>2)&3)

    // staging: chunk c = e*256 + t (e=0,1); row = e*64 + (t>>2), slot = t&3,
    // source chunk q = slot ^ ((row>>2)&3) = (t&3) ^ ((t>>4)&3)
    const int srow = t >> 2;
    const int sq = (t & 3) ^ ((t >> 4) & 3);

    // strip geometry (blocks b<64): pair p = 2048 + (b>>1), half (b&1)
    const int i0s = (32 + (b >> 1)) * 128;
    const int j0s = 63 * 128 + (b & 1) * 64;
    const bool sdiag = ((b >> 1) == 31);   // strip lies in diag tile (63,63)

    cnt[t] = 0;   // ordered before first emit by the round barriers

    auto issue = [&](int ii0, int jj0, int r_) {
        int sel = r_ & 1;   // 8 rounds/pair (even) keeps dbuf parity global
        const unsigned char* gA = hq + (size_t)(ii0 + srow) * D + r_ * 64 + sq * 16;
        const unsigned char* gB = hq + (size_t)(jj0 + srow) * D + r_ * 64 + sq * 16;
        unsigned char* lA = &tiles[sel][0][t * 16];
        unsigned char* lB = &tiles[sel][1][t * 16];
#pragma unroll
        for (int e = 0; e < 2; e++) {
            load16(gA + (size_t)(e * 64) * D, lA + e * 4096);
            load16(gB + (size_t)(e * 64) * D, lB + e * 4096);
        }
    };

    // strip staging: A full 128 rows (2 load16), B 64 rows (1 load16, all thr)
    auto issue_strip = [&](int r_) {
        int sel = r_ & 1;
        const unsigned char* gA = hq + (size_t)(i0s + srow) * D + r_ * 64 + sq * 16;
        const unsigned char* gB = hq + (size_t)(j0s + srow) * D + r_ * 64 + sq * 16;
        unsigned char* lA = &tiles[sel][0][t * 16];
#pragma unroll
        for (int e = 0; e < 2; e++)
            load16(gA + (size_t)(e * 64) * D, lA + e * 4096);
        load16(gB, &tiles[sel][1][t * 16]);   // rows 0..63 (4 KB used)
    };

    int cit, cjt;
    decode_pair(b, cit, cjt);
    int ci0 = cit * 128, cj0 = cjt * 128;
    bool cdiag = (cit == cjt);
    int ni0 = 0, nj0 = 0;
    bool ndiag = false;
    {
        int nit, njt;
        decode_pair(b + NBLK, nit, njt);
        ni0 = nit * 128; nj0 = njt * 128; ndiag = (nit == njt);
    }
    issue(ci0, cj0, 0);

    i32x16 acc[2][2];
#pragma unroll
    for (int x = 0; x < 2; x++)
#pragma unroll
        for (int y = 0; y < 2; y++)
#pragma unroll
            for (int q = 0; q < 16; q++) acc[x][y][q] = 0;

    for (int qp = 0; qp < 2; qp++) {
        for (int r = 0; r < 8; r++) {
            const int sel = r & 1;

            __builtin_amdgcn_s_barrier();   // prior reads of buffer sel done
            if (r < 7) {
                issue(ci0, cj0, r + 1);
                asm volatile("s_waitcnt vmcnt(4)" ::: "memory");  // drain round r
            } else if (qp == 0) {
                issue(ni0, nj0, 0);          // prime next pair's round 0
                asm volatile("s_waitcnt vmcnt(4)" ::: "memory");
            } else if (b < 64) {
                issue_strip(0);              // prime strip round 0 (3 loads)
                asm volatile("s_waitcnt vmcnt(3)" ::: "memory");
            } else {
                asm volatile("s_waitcnt vmcnt(0)" ::: "memory");
            }
            __builtin_amdgcn_s_barrier();   // round r fully in LDS

#pragma unroll
            for (int kk = 0; kk < 2; kk++) {   // 2 x K32 i8 MFMA steps = K64
                // lane's 16B chunk = (2kk + lg2) ^ rk  (same 4-slot swizzle)
                const int kb = (((kk << 1) | lg2) ^ rk) << 4;
                i32x4 af[2], bfr[2];
#pragma unroll
                for (int x = 0; x < 2; x++)
                    af[x] = *(const i32x4*)&tiles[sel][0][(wr + x * 32 + lm32) * 64 + kb];
#pragma unroll
                for (int y = 0; y < 2; y++)
                    bfr[y] = *(const i32x4*)&tiles[sel][1][(wc + y * 32 + lm32) * 64 + kb];
#pragma unroll
                for (int x = 0; x < 2; x++)
#pragma unroll
                    for (int y = 0; y < 2; y++)
                        acc[x][y] = __builtin_amdgcn_mfma_i32_32x32x32_i8(
                            af[x], bfr[y], acc[x][y], 0, 0, 0);
            }
        }

        // emit candidates to two-sided LDS buffer; reset acc for next pair.
        // 32x32 C/D: col = lane&31, row = (reg&3) + 8*(reg>>2) + 4*(lane>>5)
#pragma unroll
        for (int x = 0; x < 2; x++)
#pragma unroll
            for (int y = 0; y < 2; y++) {
                int lcol = wc + y * 32 + lm32;
                int gcol = cj0 + lcol;
#pragma unroll
                for (int q = 0; q < 16; q++) {
                    int rr = wr + x * 32 + (q & 3) + 8 * (q >> 2) + 4 * lg2;
                    int gi = ci0 + rr;
                    float v = (float)acc[x][y][q] * INVQ2;
                    acc[x][y][q] = 0;
                    if (gi == gcol) v = 1.0f;   // exact self-sim (diag pairs only)
                    if (v > TAU) {
                        unsigned int vb = bf16_bits_rne(v) << 16;
                        int idx = atomicAdd(&cnt[rr], 1);
                        if (idx < CAPL) lbuf[rr][idx] = vb | (unsigned int)gcol;
                        else {  // rare exact spill straight to global
                            int pg = atomicAdd(&gcnt[gi], 1);
                            if (pg < CAPG) gcand[(size_t)gi * CAPG + pg] = vb | (unsigned int)gcol;
                            else gflag[gi] = 1;
                        }
                        if (!cdiag) {   // mirrored entry for the j-side row
                            int idx2 = atomicAdd(&cnt[128 + lcol], 1);
                            if (idx2 < CAPL) lbuf[128 + lcol][idx2] = vb | (unsigned int)gi;
                            else {
                                int pg = atomicAdd(&gcnt[gcol], 1);
                                if (pg < CAPG) gcand[(size_t)gcol * CAPG + pg] = vb | (unsigned int)gi;
                                else gflag[gcol] = 1;
                            }
                        }
                    }
                }
            }

        __syncthreads();   // all emissions visible
        {
            int grow = (t < 128) ? (ci0 + t) : (cj0 + t - 128);
            int c = cnt[t];
            int s = c < CAPL ? c : CAPL;
            if (s > 0) {   // diag pairs: j-side cnt stays 0, auto-skipped
                int base = atomicAdd(&gcnt[grow], s);
                unsigned int* dst = gcand + (size_t)grow * CAPG;
                for (int k = 0; k < s; k++) {
                    int pp = base + k;
                    if (pp < CAPG) dst[pp] = lbuf[t][k];
                    else gflag[grow] = 1;
                }
            }
            cnt[t] = 0;   // owner-thread reset; next emit is 8 barriers away
        }

        ci0 = ni0; cj0 = nj0; cdiag = ndiag;
    }

    if (b >= 64) return;

    // ===== strip pass: 128 x 64 strip of pair p = 2048+(b>>1), full K ========
    // Wave w computes rows [w*32, w*32+32) x the strip's 64 cols: 2 acc.
    {
        const int wr2 = wave * 32;
        i32x16 sacc[2];
#pragma unroll
        for (int y = 0; y < 2; y++)
#pragma unroll
            for (int q = 0; q < 16; q++) sacc[y][q] = 0;

        for (int r = 0; r < 8; r++) {
            const int sel = r & 1;

            __builtin_amdgcn_s_barrier();
            if (r < 7) {
                issue_strip(r + 1);
                asm volatile("s_waitcnt vmcnt(3)" ::: "memory");  // drain round r
            } else {
                asm volatile("s_waitcnt vmcnt(0)" ::: "memory");
            }
            __builtin_amdgcn_s_barrier();

#pragma unroll
            for (int kk = 0; kk < 2; kk++) {
                const int kb = (((kk << 1) | lg2) ^ rk) << 4;
                i32x4 af = *(const i32x4*)&tiles[sel][0][(wr2 + lm32) * 64 + kb];
                i32x4 bfr[2];
#pragma unroll
                for (int y = 0; y < 2; y++)
                    bfr[y] = *(const i32x4*)&tiles[sel][1][(y * 32 + lm32) * 64 + kb];
#pragma unroll
                for (int y = 0; y < 2; y++)
                    sacc[y] = __builtin_amdgcn_mfma_i32_32x32x32_i8(
                        af, bfr[y], sacc[y], 0, 0, 0);
            }
        }

        // emit: i-side rows 0..127 -> cnt[rr]; j-side strip cols -> cnt[128+lcol]
#pragma unroll
        for (int y = 0; y < 2; y++) {
            int lcol = y * 32 + lm32;            // 0..63 within strip
            int gcol = j0s + lcol;
#pragma unroll
            for (int q = 0; q < 16; q++) {
                int rr = wr2 + (q & 3) + 8 * (q >> 2) + 4 * lg2;
                int gi = i0s + rr;
                float v = (float)sacc[y][q] * INVQ2;
                if (gi == gcol) v = 1.0f;        // diag-tile strips only
                if (v > TAU) {
                    unsigned int vb = bf16_bits_rne(v) << 16;
                    int idx = atomicAdd(&cnt[rr], 1);
                    if (idx < CAPL) lbuf[rr][idx] = vb | (unsigned int)gcol;
                    else {
                        int pg = atomicAdd(&gcnt[gi], 1);
                        if (pg < CAPG) gcand[(size_t)gi * CAPG + pg] = vb | (unsigned int)gcol;
                        else gflag[gi] = 1;
                    }
                    if (!sdiag) {
                        int idx2 = atomicAdd(&cnt[128 + lcol], 1);
                        if (idx2 < CAPL) lbuf[128 + lcol][idx2] = vb | (unsigned int)gi;
                        else {
                            int pg = atomicAdd(&gcnt[gcol], 1);
                            if (pg < CAPG) gcand[(size_t)gcol * CAPG + pg] = vb | (unsigned int)gi;
                            else gflag[gcol] = 1;
                        }
                    }
                }
            }
        }

        __syncthreads();
        if (t < 192) {   // 128 i-rows + 64 j-cols
            int grow = (t < 128) ? (i0s + t) : (j0s + t - 128);
            int c = cnt[t];
            int s = c < CAPL ? c : CAPL;
            if (s > 0) {
                int base = atomicAdd(&gcnt[grow], s);
                unsigned int* dst = gcand + (size_t)grow * CAPG;
                for (int k = 0; k < s; k++) {
                    int pp = base + k;
                    if (pp < CAPG) dst[pp] = lbuf[t][k];
                    else gflag[grow] = 1;
                }
            }
        }
    }
}

// -- Kernel 2: exact top-12 + softmax + gather (i8 neighbors, fp32 self) --
__global__ __launch_bounds__(256) void gather_kernel(const float* __restrict__ h,
                                                     const unsigned char* __restrict__ hq,
                                                     const float* __restrict__ norms,
                                                     const unsigned int* __restrict__ gcand,
                                                     const int* __restrict__ gcnt,
                                                     const int* __restrict__ gflag,
                                                     float* __restrict__ out) {
    int row = blockIdx.x * 4 + (threadIdx.x >> 6);
    int lane = threadIdx.x & 63;

    // early self-row prefetch: row is always its own top-1 (sim = 1.0)
    const float4* hr4 = (const float4*)(h + (size_t)row * D);
    float4 s0 = hr4[lane], s1 = hr4[64 + lane];

    int c = gcnt[row];

    float selv[K_TOP];
    int selj[K_TOP];

    if (c >= K_TOP && c <= CAPG && gflag[row] == 0) {
        const unsigned int* cr = gcand + (size_t)row * CAPG;
        unsigned int e[3];
#pragma unroll
        for (int q = 0; q < 3; q++) {
            int idx = lane + 64 * q;
            e[q] = (idx < c) ? cr[idx] : 0u;
        }
#pragma unroll
        for (int k = 0; k < K_TOP; k++) {
            unsigned int m = e[0];
            if (e[1] > m) m = e[1];
            if (e[2] > m) m = e[2];
#pragma unroll
            for (int off = 32; off > 0; off >>= 1) {
                unsigned int om = __shfl_xor(m, off, 64);
                if (om > m) m = om;
            }
            selv[k] = __uint_as_float(m & 0xFFFF0000u);
            selj[k] = (int)(m & 0x1FFFu);
#pragma unroll
            for (int q = 0; q < 3; q++)
                if (e[q] == m) e[q] = 0u;   // entries unique (distinct cols)
        }
    } else {
        // exact brute-force fallback over i8 rows (rare; cheap insurance)
        float vals[K_TOP];
        int idxs[K_TOP];
#pragma unroll
        for (int q = 0; q < K_TOP; q++) { vals[q] = -3e38f; idxs[q] = 0; }
        float minv = -3e38f;
        int minp = 0;
        const unsigned int* rp = (const unsigned int*)(hq + (size_t)row * D);
        for (int col = lane; col < N; col += 64) {
            const unsigned int* cp = (const unsigned int*)(hq + (size_t)col * D);
            int isum = 0;
            for (int k4 = 0; k4 < D / 4; k4++) {
                unsigned int ra = rp[k4], ca = cp[k4];
                isum += sb(ra, 0) * sb(ca, 0) + sb(ra, 1) * sb(ca, 1) +
                        sb(ra, 2) * sb(ca, 2) + sb(ra, 3) * sb(ca, 3);
            }
            float s = (float)isum * INVQ2;
            if (col == row) s = 1.0f;
            if (s > minv) {
                vals[minp] = s; idxs[minp] = col;
                minv = vals[0]; minp = 0;
#pragma unroll
                for (int q = 1; q < K_TOP; q++)
                    if (vals[q] < minv) { minv = vals[q]; minp = q; }
            }
        }
        for (int k = 0; k < K_TOP; k++) {
            float bv = vals[0]; int bp = 0;
#pragma unroll
            for (int q = 1; q < K_TOP; q++)
                if (vals[q] > bv) { bv = vals[q]; bp = q; }
            float v = bv; int j = idxs[bp]; int src = lane;
#pragma unroll
            for (int off = 32; off > 0; off >>= 1) {
                float ov = __shfl_xor(v, off, 64);
                int oj = __shfl_xor(j, off, 64);
                int os = __shfl_xor(src, off, 64);
                if (ov > v || (ov == v && os < src)) { v = ov; j = oj; src = os; }
            }
            selv[k] = __uint_as_float((unsigned int)(bf16_bits_rne(v) << 16));
            selj[k] = j;
            if (lane == src) vals[bp] = -3e38f;
        }
    }

    // batch-issue all neighbor i8 row loads (12-deep MLP) + their norms
    unsigned int na[K_TOP], nb[K_TOP];
    float wn[K_TOP];
#pragma unroll
    for (int q = 0; q < K_TOP; q++) {
        const unsigned int* r32 = (const unsigned int*)(hq + (size_t)selj[q] * D);
        na[q] = r32[lane];
        nb[q] = r32[64 + lane];
        wn[q] = norms[selj[q]];
    }

    float mx = selv[0];
    float beta[K_TOP];
    float sum = 0.f;
#pragma unroll
    for (int q = 0; q < K_TOP; q++) { beta[q] = __expf(THETA * (selv[q] - mx)); sum += beta[q]; }
    float rs = 1.0f / sum;

    // lane owns output elems [lane*4,+4) and [256+lane*4,+4)
    float acc[8];
#pragma unroll
    for (int ee = 0; ee < 8; ee++) acc[ee] = 0.f;
#pragma unroll
    for (int q = 0; q < K_TOP; q++) {
        float w = beta[q] * rs;
        if (selj[q] == row) {   // wave-uniform; dominant term stays fp32-exact
            acc[0] += w * s0.x; acc[1] += w * s0.y; acc[2] += w * s0.z; acc[3] += w * s0.w;
            acc[4] += w * s1.x; acc[5] += w * s1.y; acc[6] += w * s1.z; acc[7] += w * s1.w;
        } else {                // neighbors (weight ~2e-4): i8 row x norm/127
            float wj = w * wn[q] * (1.0f / 127.0f);
            acc[0] += wj * (float)sb(na[q], 0);
            acc[1] += wj * (float)sb(na[q], 1);
            acc[2] += wj * (float)sb(na[q], 2);
            acc[3] += wj * (float)sb(na[q], 3);
            acc[4] += wj * (float)sb(nb[q], 0);
            acc[5] += wj * (float)sb(nb[q], 1);
            acc[6] += wj * (float)sb(nb[q], 2);
            acc[7] += wj * (float)sb(nb[q], 3);
        }
    }
    float4* o4 = (float4*)(out + (size_t)row * D);
    o4[lane] = make_float4(acc[0], acc[1], acc[2], acc[3]);
    o4[64 + lane] = make_float4(acc[4], acc[5], acc[6], acc[7]);
}

extern "C" void kernel_launch(void* const* d_in, const int* in_sizes, int n_in,
                              void* d_out, int out_size, void* d_ws, size_t ws_size,
                              hipStream_t stream) {
    const float* h = (const float*)d_in[0];
    float* out = (float*)d_out;

    char* ws = (char*)d_ws;
    unsigned char* hq = (unsigned char*)ws;                      // 4 MB i8
    size_t off = (size_t)N * D;
    float* norms = (float*)(ws + off);                           // 32 KB
    int* gcnt = (int*)(ws + off + (size_t)N * 4);                // 32 KB
    int* gflag = (int*)(ws + off + (size_t)N * 8);               // 32 KB
    unsigned int* gcand = (unsigned int*)(ws + off + (size_t)N * 12);  // 6 MB

    norm_kernel<<<N / 4, 256, 0, stream>>>(h, hq, norms, gcnt, gflag);
    simfp8_kernel<<<NBLK, 256, 0, stream>>>(hq, gcand, gcnt, gflag);
    gather_kernel<<<N / 4, 256, 0, stream>>>(h, hq, norms, gcand, gcnt, gflag, out);
}